// Round 8
// baseline (378.072 us; speedup 1.0000x reference)
//
#include <hip/hip_runtime.h>
#include <hip/hip_bf16.h>

#define N_NODES 40000
#define N_EDGES 640000
#define HIDDEN  128
#define NUM_RBF 50
#define NBLK_SCAN 157  // ceil(40000/256)

typedef __attribute__((ext_vector_type(8))) short bf16x8;
typedef __attribute__((ext_vector_type(4))) float f32x4;

__device__ __forceinline__ short f2bf(float f) {
  __hip_bfloat16 h = __float2bfloat16(f);
  return (short)__builtin_bit_cast(unsigned short, h);
}
__device__ __forceinline__ float bf2f(unsigned short u) {
  unsigned int v = ((unsigned int)u) << 16;
  return __builtin_bit_cast(float, v);
}
__device__ __forceinline__ float bflo(unsigned int u) {
  return __builtin_bit_cast(float, u << 16);
}
__device__ __forceinline__ float bfhi(unsigned int u) {
  return __builtin_bit_cast(float, u & 0xffff0000u);
}
__device__ __forceinline__ unsigned int pack2bf(float a, float b) {
  return (unsigned int)(unsigned short)f2bf(a) |
         ((unsigned int)(unsigned short)f2bf(b) << 16);
}

__device__ __forceinline__ float fast_tanh(float x) {
  float e = __expf(2.0f * x);
  return 1.0f - 2.0f * __builtin_amdgcn_rcpf(e + 1.0f);
}

__device__ __forceinline__ f32x4 mfma16(bf16x8 a, bf16x8 b, f32x4 c) {
  return __builtin_amdgcn_mfma_f32_16x16x32_bf16(a, b, c, 0, 0, 0);
}

__device__ __forceinline__ bf16x8 load8_f32_bf16(const float* p) {
  const float4 v0 = ((const float4*)p)[0];
  const float4 v1 = ((const float4*)p)[1];
  bf16x8 r;
  r[0] = f2bf(v0.x); r[1] = f2bf(v0.y); r[2] = f2bf(v0.z); r[3] = f2bf(v0.w);
  r[4] = f2bf(v1.x); r[5] = f2bf(v1.y); r[6] = f2bf(v1.z); r[7] = f2bf(v1.w);
  return r;
}

// ---------------- CSR build ----------------
__global__ __launch_bounds__(256) void hist_kernel(const int* __restrict__ ei,
                                                   int* __restrict__ hist) {
  int e = blockIdx.x * 256 + threadIdx.x;
  if (e < N_EDGES) atomicAdd(&hist[ei[N_EDGES + e]], 1);
}

__global__ __launch_bounds__(256) void scan1_kernel(const int* __restrict__ hist,
                                                    int* __restrict__ tmp,
                                                    int* __restrict__ bsum) {
  __shared__ int ls[256];
  const int t = threadIdx.x;
  const int i = blockIdx.x * 256 + t;
  int v = (i < N_NODES) ? hist[i] : 0;
  ls[t] = v;
  __syncthreads();
  for (int off = 1; off < 256; off <<= 1) {
    int u = (t >= off) ? ls[t - off] : 0;
    __syncthreads();
    ls[t] += u;
    __syncthreads();
  }
  if (i < N_NODES) tmp[i] = ls[t];
  if (t == 255) bsum[blockIdx.x] = ls[255];
}

__global__ __launch_bounds__(256) void scan2_kernel(const int* __restrict__ bsum,
                                                    int* __restrict__ bpfx,
                                                    int* __restrict__ row_start) {
  __shared__ int ls[256];
  const int t = threadIdx.x;
  int v = (t < NBLK_SCAN) ? bsum[t] : 0;
  ls[t] = v;
  __syncthreads();
  for (int off = 1; off < 256; off <<= 1) {
    int u = (t >= off) ? ls[t - off] : 0;
    __syncthreads();
    ls[t] += u;
    __syncthreads();
  }
  if (t < NBLK_SCAN) bpfx[t] = ls[t] - v;
  if (t == 255) row_start[N_NODES] = ls[255];
}

__global__ __launch_bounds__(256) void scan3_kernel(const int* __restrict__ hist,
                                                    const int* __restrict__ tmp,
                                                    const int* __restrict__ bpfx,
                                                    int* __restrict__ row_start,
                                                    int* __restrict__ cursor) {
  const int i = blockIdx.x * 256 + threadIdx.x;
  if (i < N_NODES) {
    int rs = tmp[i] - hist[i] + bpfx[blockIdx.x];
    row_start[i] = rs;
    cursor[i] = rs;
  }
}

// build dst-sorted (edge, src) pairs
__global__ __launch_bounds__(256) void perm_kernel(const int* __restrict__ ei,
                                                   int* __restrict__ cursor,
                                                   int2* __restrict__ epk) {
  int e = blockIdx.x * 256 + threadIdx.x;
  if (e < N_EDGES) {
    int dst = ei[N_EDGES + e];
    int pos = atomicAdd(&cursor[dst], 1);
    epk[pos] = make_int2(e, ei[e]);
  }
}

// ---------------- kernel 1: hb = bf16(x @ W_in), direct stores (R3-proven mapping) ----------------
__global__ __launch_bounds__(256) void hproj_kernel(
    const float* __restrict__ x, const float* __restrict__ W_in,
    unsigned short* __restrict__ hb)
{
  __shared__ __align__(16) unsigned short sWt[128 * 136];
  const int tid = threadIdx.x, wave = tid >> 6, lane = tid & 63;
  const int ln = lane & 15, grp = lane >> 4;
  const int r0 = blockIdx.x * 64;

  for (int idx = tid; idx < 128 * 128; idx += 256) {
    int k = idx >> 7, c = idx & 127;
    sWt[c * 136 + k] = f2bf(W_in[idx]);
  }
  __syncthreads();

  const size_t r = (size_t)r0 + wave * 16 + ln;
  f32x4 acc[8];
#pragma unroll
  for (int ct = 0; ct < 8; ++ct) acc[ct] = (f32x4){0.f, 0.f, 0.f, 0.f};
#pragma unroll
  for (int ks = 0; ks < 4; ++ks) {
    bf16x8 a = load8_f32_bf16(&x[r * 128 + ks * 32 + grp * 8]);
#pragma unroll
    for (int ct = 0; ct < 8; ++ct) {
      bf16x8 b = *(const bf16x8*)&sWt[(ct * 16 + ln) * 136 + ks * 32 + grp * 8];
      acc[ct] = mfma16(a, b, acc[ct]);
    }
  }
#pragma unroll
  for (int ct = 0; ct < 8; ++ct) {
#pragma unroll
    for (int i = 0; i < 4; ++i) {
      hb[(size_t)(r0 + wave * 16 + grp * 4 + i) * 128 + ct * 16 + ln] =
          (unsigned short)f2bf(acc[ct][i]);
    }
  }
}

// ---------------- kernel 2: Wf filter MLP; weights in REGISTERS, small LDS, high occupancy ----------------
__global__ __launch_bounds__(256) void filt_kernel(
    const float* __restrict__ edge_attr,
    const float* __restrict__ edge_weight,
    const float* __restrict__ W_f1, const float* __restrict__ b_f1,
    const float* __restrict__ W_f2, const float* __restrict__ b_f2,
    unsigned short* __restrict__ Wf)
{
  __shared__ __align__(16) unsigned short sBuf[64 * 136];  // 17.4 KB, reused
  __shared__ float sb1[128], sb2[128], sC[64];

  const int tid = threadIdx.x, wave = tid >> 6, lane = tid & 63;
  const int ln = lane & 15, grp = lane >> 4;

  if (tid < 128) { sb1[tid] = b_f1[tid]; sb2[tid] = b_f2[tid]; }

  bf16x8 w1f[8][2];   // W1^T fragments, loop-invariant
  bf16x8 w2f[8][4];   // W2^T fragments, loop-invariant

  // ---- stage W1^T through sBuf in 2 half-column passes ----
#pragma unroll
  for (int h = 0; h < 2; ++h) {
    __syncthreads();  // protect previous pass's reads (and sb writes pass 0)
    for (int idx = tid; idx < 64 * 64; idx += 256) {
      int c = idx >> 6, k = idx & 63;
      sBuf[c * 72 + k] = (k < NUM_RBF)
          ? (unsigned short)f2bf(W_f1[k * 128 + h * 64 + c]) : (unsigned short)0;
    }
    __syncthreads();
#pragma unroll
    for (int ct2 = 0; ct2 < 4; ++ct2) {
      int cl = ct2 * 16 + ln;
      w1f[h * 4 + ct2][0] = *(const bf16x8*)&sBuf[cl * 72 + grp * 8];
      w1f[h * 4 + ct2][1] = *(const bf16x8*)&sBuf[cl * 72 + 32 + grp * 8];
    }
  }
  // ---- stage W2^T through sBuf in 2 half-column passes ----
#pragma unroll
  for (int h = 0; h < 2; ++h) {
    __syncthreads();
    for (int idx = tid; idx < 64 * 128; idx += 256) {
      int c = idx >> 7, k = idx & 127;
      sBuf[c * 136 + k] = (unsigned short)f2bf(W_f2[k * 128 + h * 64 + c]);
    }
    __syncthreads();
#pragma unroll
    for (int ct2 = 0; ct2 < 4; ++ct2) {
      int cl = ct2 * 16 + ln;
#pragma unroll
      for (int ks = 0; ks < 4; ++ks)
        w2f[h * 4 + ct2][ks] = *(const bf16x8*)&sBuf[cl * 136 + ks * 32 + grp * 8];
    }
  }
  __syncthreads();

  const int nTiles = N_EDGES / 64;
  for (int tile = blockIdx.x; tile < nTiles; tile += gridDim.x) {
    const int e0 = tile * 64;
    // stage edge_attr tile as bf16 via float2 loads (R3/R7-proven)
    for (int idx = tid; idx < 64 * 25; idx += 256) {
      int e = idx / 25, k = 2 * (idx - e * 25);
      float2 v = ((const float2*)edge_attr)[(size_t)e0 * 25 + idx];
      *(unsigned int*)&sBuf[e * 136 + k] = pack2bf(v.x, v.y);
    }
    for (int idx = tid; idx < 64 * 7; idx += 256) {
      int e = idx / 7, k = NUM_RBF + 2 * (idx - e * 7);
      *(unsigned int*)&sBuf[e * 136 + k] = 0;  // zero-pad k in [50,64)
    }
    if (tid < 64)
      sC[tid] = 0.5f * (__cosf(edge_weight[e0 + tid] * 0.31415926535f) + 1.0f);
    __syncthreads();  // (1) staging visible

    const int erow = wave * 16 + ln;
    bf16x8 a0 = *(const bf16x8*)&sBuf[erow * 136 + grp * 8];
    bf16x8 a1 = *(const bf16x8*)&sBuf[erow * 136 + 32 + grp * 8];
    __syncthreads();  // (2) frag reads done before overwrite

    // ---- GEMM1: T = tanh(A @ W1 + b1) ----
#pragma unroll
    for (int ct = 0; ct < 8; ++ct) {
      f32x4 z = {0.f, 0.f, 0.f, 0.f};
      z = mfma16(a0, w1f[ct][0], z);
      z = mfma16(a1, w1f[ct][1], z);
      int c = ct * 16 + ln;
      float bias = sb1[c];
#pragma unroll
      for (int i = 0; i < 4; ++i) {
        int rl = wave * 16 + grp * 4 + i;
        sBuf[rl * 136 + c] = (unsigned short)f2bf(fast_tanh(z[i] + bias));
      }
    }
    __syncthreads();  // (3) T short-writes fenced before vector reads

    // ---- GEMM2: Wf = (T @ W2 + b2) * C ----
    bf16x8 af[4];
#pragma unroll
    for (int ks = 0; ks < 4; ++ks)
      af[ks] = *(const bf16x8*)&sBuf[erow * 136 + ks * 32 + grp * 8];
#pragma unroll
    for (int ct = 0; ct < 8; ++ct) {
      f32x4 z = {0.f, 0.f, 0.f, 0.f};
#pragma unroll
      for (int ks = 0; ks < 4; ++ks)
        z = mfma16(af[ks], w2f[ct][ks], z);
      int c = ct * 16 + ln;
      float bias = sb2[c];
#pragma unroll
      for (int i = 0; i < 4; ++i) {
        int el = wave * 16 + grp * 4 + i;
        sBuf[el * 136 + c] = (unsigned short)f2bf((z[i] + bias) * sC[el]);
      }
    }
    __syncthreads();  // (4) Wf short-writes fenced before uint writeout reads

    // ---- coalesced contiguous writeout: own 16 rows x 256B ----
#pragma unroll
    for (int j = 0; j < 16; ++j) {
      ((unsigned int*)Wf)[(size_t)(e0 + wave * 16 + j) * 64 + lane] =
          *(const unsigned int*)&sBuf[(wave * 16 + j) * 136 + lane * 2];
    }
    __syncthreads();  // (5) writeout reads done before next-tile staging
  }
}

// ---------------- kernel 3: agg (f32, full d_out rows) = segment-sum(Wf[e] * h[src]) ----------------
__global__ __launch_bounds__(256) void gather_kernel(
    const int* __restrict__ row_start,
    const int2* __restrict__ epk,
    const unsigned int* __restrict__ Wf32,
    const unsigned int* __restrict__ hb32,
    float* __restrict__ aggf)   // = d_out, full f32 rows
{
  const int node = blockIdx.x * 4 + (threadIdx.x >> 6);
  const int lane = threadIdx.x & 63;
  int i = row_start[node];
  const int ee = row_start[node + 1];
  float ax = 0.f, ay = 0.f, bx = 0.f, by = 0.f;
  for (; i + 1 < ee; i += 2) {
    int2 p0 = epk[i];
    int2 p1 = epk[i + 1];
    unsigned int w0 = Wf32[(size_t)p0.x * 64 + lane];
    unsigned int h0 = hb32[(size_t)p0.y * 64 + lane];
    unsigned int w1 = Wf32[(size_t)p1.x * 64 + lane];
    unsigned int h1 = hb32[(size_t)p1.y * 64 + lane];
    ax = fmaf(bflo(w0), bflo(h0), ax);
    ay = fmaf(bfhi(w0), bfhi(h0), ay);
    bx = fmaf(bflo(w1), bflo(h1), bx);
    by = fmaf(bfhi(w1), bfhi(h1), by);
  }
  if (i < ee) {
    int2 p0 = epk[i];
    unsigned int w0 = Wf32[(size_t)p0.x * 64 + lane];
    unsigned int h0 = hb32[(size_t)p0.y * 64 + lane];
    ax = fmaf(bflo(w0), bflo(h0), ax);
    ay = fmaf(bfhi(w0), bfhi(h0), ay);
  }
  ((float2*)aggf)[(size_t)node * 64 + lane] = make_float2(ax + bx, ay + by);
}

// ---------------- kernel 4 (R3-proven): out = tanh(agg@W_out+b_out) @ W_lin + b_lin ----------------
// agg and out may alias (both = d_out): no __restrict__, block-local rows only.
__global__ __launch_bounds__(256) void tail_kernel(
    const float* agg,
    const float* __restrict__ W_out, const float* __restrict__ b_out,
    const float* __restrict__ W_lin, const float* __restrict__ b_lin,
    float* out)
{
  __shared__ __align__(16) unsigned short sWo[128 * 136];
  __shared__ __align__(16) unsigned short sWl[128 * 136];
  __shared__ __align__(16) unsigned short sT[64 * 136];
  __shared__ float sbo[128], sbl[128];
  const int tid = threadIdx.x, wave = tid >> 6, lane = tid & 63;
  const int ln = lane & 15, grp = lane >> 4;
  const int r0 = blockIdx.x * 64;

  for (int idx = tid; idx < 128 * 128; idx += 256) {
    int k = idx >> 7, c = idx & 127;
    sWo[c * 136 + k] = f2bf(W_out[idx]);
    sWl[c * 136 + k] = f2bf(W_lin[idx]);
  }
  if (tid < 128) { sbo[tid] = b_out[tid]; sbl[tid] = b_lin[tid]; }
  __syncthreads();

  const size_t r = (size_t)r0 + wave * 16 + ln;
  f32x4 acc[8];
#pragma unroll
  for (int ct = 0; ct < 8; ++ct) acc[ct] = (f32x4){0.f, 0.f, 0.f, 0.f};
#pragma unroll
  for (int ks = 0; ks < 4; ++ks) {
    bf16x8 a = load8_f32_bf16(&agg[r * 128 + ks * 32 + grp * 8]);
#pragma unroll
    for (int ct = 0; ct < 8; ++ct) {
      bf16x8 b = *(const bf16x8*)&sWo[(ct * 16 + ln) * 136 + ks * 32 + grp * 8];
      acc[ct] = mfma16(a, b, acc[ct]);
    }
  }
#pragma unroll
  for (int ct = 0; ct < 8; ++ct) {
    int c = ct * 16 + ln;
    float bias = sbo[c];
#pragma unroll
    for (int i = 0; i < 4; ++i) {
      int rl = wave * 16 + grp * 4 + i;
      sT[rl * 136 + c] = f2bf(fast_tanh(acc[ct][i] + bias));
    }
  }
  __syncthreads();

  bf16x8 af[4];
#pragma unroll
  for (int ks = 0; ks < 4; ++ks)
    af[ks] = *(const bf16x8*)&sT[(wave * 16 + ln) * 136 + ks * 32 + grp * 8];
  f32x4 acc2[8];
#pragma unroll
  for (int ct = 0; ct < 8; ++ct) {
    f32x4 z = {0.f, 0.f, 0.f, 0.f};
    int c = ct * 16 + ln;
#pragma unroll
    for (int ks = 0; ks < 4; ++ks) {
      bf16x8 b = *(const bf16x8*)&sWl[c * 136 + ks * 32 + grp * 8];
      z = mfma16(af[ks], b, z);
    }
    acc2[ct] = z;
  }
  __syncthreads();  // all agg reads done before overwriting rows
#pragma unroll
  for (int ct = 0; ct < 8; ++ct) {
    int c = ct * 16 + ln;
    float bias = sbl[c];
#pragma unroll
    for (int i = 0; i < 4; ++i) {
      out[(size_t)(r0 + wave * 16 + grp * 4 + i) * 128 + c] = acc2[ct][i] + bias;
    }
  }
}

// ================= fallback path (atomic, bf16 h) =================
__global__ __launch_bounds__(256, 2) void edge_kernel(
    const float* __restrict__ edge_attr,
    const int*   __restrict__ edge_index,
    const float* __restrict__ edge_weight,
    const float* __restrict__ W_f1, const float* __restrict__ b_f1,
    const float* __restrict__ W_f2, const float* __restrict__ b_f2,
    const unsigned short* __restrict__ hb, float* __restrict__ agg)
{
  __shared__ __align__(16) unsigned short sW1t[128 * 72];
  __shared__ __align__(16) unsigned short sW2t[128 * 136];
  __shared__ __align__(16) unsigned short sT[64 * 136];
  __shared__ float sb1[128], sb2[128], sC[64];
  __shared__ int sSrc[64], sDst[64];

  const int tid = threadIdx.x, wave = tid >> 6, lane = tid & 63;
  const int ln = lane & 15, grp = lane >> 4;

  for (int idx = tid; idx < 128 * 64; idx += 256) {
    int k = idx >> 7, c = idx & 127;
    sW1t[c * 72 + k] = (k < NUM_RBF) ? f2bf(W_f1[k * 128 + c]) : (short)0;
  }
  for (int idx = tid; idx < 128 * 128; idx += 256) {
    int k = idx >> 7, c = idx & 127;
    sW2t[c * 136 + k] = f2bf(W_f2[idx]);
  }
  if (tid < 128) { sb1[tid] = b_f1[tid]; sb2[tid] = b_f2[tid]; }

  const int nTiles = N_EDGES / 64;
  for (int tile = blockIdx.x; tile < nTiles; tile += gridDim.x) {
    const int e0 = tile * 64;
    for (int idx = tid; idx < 64 * NUM_RBF; idx += 256) {
      int e = idx / NUM_RBF, k = idx - e * NUM_RBF;
      sT[e * 136 + k] = f2bf(edge_attr[(size_t)e0 * NUM_RBF + idx]);
    }
    for (int idx = tid; idx < 64 * 14; idx += 256) {
      int e = idx / 14, k = NUM_RBF + (idx - (idx / 14) * 14);
      sT[e * 136 + k] = 0;
    }
    if (tid < 64) {
      int e = e0 + tid;
      sC[tid] = 0.5f * (__cosf(edge_weight[e] * 0.31415926535f) + 1.0f);
      sSrc[tid] = edge_index[e];
      sDst[tid] = edge_index[N_EDGES + e];
    }
    __syncthreads();

    const int erow = wave * 16 + ln;
    bf16x8 a0 = *(const bf16x8*)&sT[erow * 136 + grp * 8];
    bf16x8 a1 = *(const bf16x8*)&sT[erow * 136 + 32 + grp * 8];
    __syncthreads();

    f32x4 acc[8];
#pragma unroll
    for (int ct = 0; ct < 8; ++ct) {
      f32x4 z = {0.f, 0.f, 0.f, 0.f};
      int c = ct * 16 + ln;
      bf16x8 b0 = *(const bf16x8*)&sW1t[c * 72 + grp * 8];
      bf16x8 b1 = *(const bf16x8*)&sW1t[c * 72 + 32 + grp * 8];
      z = mfma16(a0, b0, z);
      z = mfma16(a1, b1, z);
      acc[ct] = z;
    }
#pragma unroll
    for (int ct = 0; ct < 8; ++ct) {
      int c = ct * 16 + ln;
      float bias = sb1[c];
#pragma unroll
      for (int i = 0; i < 4; ++i) {
        int el = wave * 16 + grp * 4 + i;
        sT[el * 136 + c] = f2bf(fast_tanh(acc[ct][i] + bias));
      }
    }
    __syncthreads();

    bf16x8 af[4];
#pragma unroll
    for (int ks = 0; ks < 4; ++ks)
      af[ks] = *(const bf16x8*)&sT[erow * 136 + ks * 32 + grp * 8];
    f32x4 acc2[8];
#pragma unroll
    for (int ct = 0; ct < 8; ++ct) {
      f32x4 z = {0.f, 0.f, 0.f, 0.f};
      int c = ct * 16 + ln;
#pragma unroll
      for (int ks = 0; ks < 4; ++ks) {
        bf16x8 b = *(const bf16x8*)&sW2t[c * 136 + ks * 32 + grp * 8];
        z = mfma16(af[ks], b, z);
      }
      acc2[ct] = z;
    }
#pragma unroll
    for (int ct = 0; ct < 8; ++ct) {
      int c = ct * 16 + ln;
      float bias = sb2[c];
#pragma unroll
      for (int i = 0; i < 4; ++i) {
        int el = wave * 16 + grp * 4 + i;
        float wf = (acc2[ct][i] + bias) * sC[el];
        float m = bf2f(hb[(size_t)sSrc[el] * 128 + c]) * wf;
        atomicAdd(&agg[(size_t)sDst[el] * 128 + c], m);
      }
    }
    __syncthreads();
  }
}

extern "C" void kernel_launch(void* const* d_in, const int* in_sizes, int n_in,
                              void* d_out, int out_size, void* d_ws, size_t ws_size,
                              hipStream_t stream) {
  const float* x     = (const float*)d_in[0];
  const int*   ei    = (const int*)d_in[1];
  const float* ew    = (const float*)d_in[2];
  const float* ea    = (const float*)d_in[3];
  const float* W_f1  = (const float*)d_in[4];
  const float* b_f1  = (const float*)d_in[5];
  const float* W_f2  = (const float*)d_in[6];
  const float* b_f2  = (const float*)d_in[7];
  const float* W_in  = (const float*)d_in[8];
  const float* W_out = (const float*)d_in[9];
  const float* b_out = (const float*)d_in[10];
  const float* W_lin = (const float*)d_in[11];
  const float* b_lin = (const float*)d_in[12];

  const size_t HB_B  = (size_t)N_NODES * HIDDEN * 2;    // 10.24 MB  bf16 h
  const size_t WF_B  = (size_t)N_EDGES * HIDDEN * 2;    // 163.84 MB bf16 Wf
  const size_t I_B   = (size_t)N_NODES * 4;             // 160 KB
  const size_t RS_B  = ((size_t)(N_NODES + 1) * 4 + 15) & ~(size_t)15;
  const size_t SB_B  = 1024;
  const size_t EPK_B = (size_t)N_EDGES * 8;             // 5.12 MB
  const size_t NEED = HB_B + WF_B + I_B + RS_B + I_B + I_B + SB_B + SB_B + EPK_B;

  char* ws = (char*)d_ws;
  unsigned short* hb = (unsigned short*)ws;

  if (ws_size >= NEED) {
    char* q = ws + HB_B;
    unsigned short* Wf = (unsigned short*)q;  q += WF_B;
    int* hist      = (int*)q;                 q += I_B;
    int* row_start = (int*)q;                 q += RS_B;
    int* cursor    = (int*)q;                 q += I_B;
    int* tmp       = (int*)q;                 q += I_B;
    int* bsum      = (int*)q;                 q += SB_B;
    int* bpfx      = (int*)q;                 q += SB_B;
    int2* epk      = (int2*)q;

    hipMemsetAsync(hist, 0, I_B, stream);
    hist_kernel<<<(N_EDGES + 255) / 256, 256, 0, stream>>>(ei, hist);
    scan1_kernel<<<NBLK_SCAN, 256, 0, stream>>>(hist, tmp, bsum);
    scan2_kernel<<<1, 256, 0, stream>>>(bsum, bpfx, row_start);
    scan3_kernel<<<NBLK_SCAN, 256, 0, stream>>>(hist, tmp, bpfx, row_start, cursor);
    perm_kernel<<<(N_EDGES + 255) / 256, 256, 0, stream>>>(ei, cursor, epk);
    hproj_kernel<<<N_NODES / 64, 256, 0, stream>>>(x, W_in, hb);
    filt_kernel<<<1536, 256, 0, stream>>>(ea, ew, W_f1, b_f1, W_f2, b_f2, Wf);
    gather_kernel<<<N_NODES / 4, 256, 0, stream>>>(row_start, epk,
                                                   (const unsigned int*)Wf,
                                                   (const unsigned int*)hb,
                                                   (float*)d_out);
    tail_kernel<<<N_NODES / 64, 256, 0, stream>>>((const float*)d_out,
                                                  W_out, b_out, W_lin, b_lin,
                                                  (float*)d_out);
  } else {
    float* agg = (float*)(ws + HB_B);
    hipMemsetAsync(agg, 0, (size_t)N_NODES * HIDDEN * 4, stream);
    hproj_kernel<<<N_NODES / 64, 256, 0, stream>>>(x, W_in, hb);
    edge_kernel<<<512, 256, 0, stream>>>(ea, ei, ew, W_f1, b_f1, W_f2, b_f2, hb, agg);
    tail_kernel<<<N_NODES / 64, 256, 0, stream>>>(agg, W_out, b_out, W_lin, b_lin,
                                                  (float*)d_out);
  }
}

// Round 9
// 289.994 us; speedup vs baseline: 1.3037x; 1.3037x over previous
//
#include <hip/hip_runtime.h>
#include <hip/hip_bf16.h>

#define N_NODES 40000
#define N_EDGES 640000
#define HIDDEN  128
#define NUM_RBF 50
#define NBLK_SCAN 157  // ceil(40000/256)

typedef __attribute__((ext_vector_type(8))) short bf16x8;
typedef __attribute__((ext_vector_type(4))) float f32x4;

// zero-runtime compiler fence: orders LDS short-writes before differently-typed
// reads within a wave (TBAA otherwise allows reordering — the R4-R6 bug)
#define WAVE_FENCE() do { asm volatile("" ::: "memory"); \
                          __builtin_amdgcn_sched_barrier(0); } while (0)

__device__ __forceinline__ short f2bf(float f) {
  __hip_bfloat16 h = __float2bfloat16(f);
  return (short)__builtin_bit_cast(unsigned short, h);
}
__device__ __forceinline__ float bf2f(unsigned short u) {
  unsigned int v = ((unsigned int)u) << 16;
  return __builtin_bit_cast(float, v);
}
__device__ __forceinline__ float bflo(unsigned int u) {
  return __builtin_bit_cast(float, u << 16);
}
__device__ __forceinline__ float bfhi(unsigned int u) {
  return __builtin_bit_cast(float, u & 0xffff0000u);
}
__device__ __forceinline__ unsigned int pack2bf(float a, float b) {
  return (unsigned int)(unsigned short)f2bf(a) |
         ((unsigned int)(unsigned short)f2bf(b) << 16);
}

__device__ __forceinline__ float fast_tanh(float x) {
  float e = __expf(2.0f * x);
  return 1.0f - 2.0f * __builtin_amdgcn_rcpf(e + 1.0f);
}

__device__ __forceinline__ f32x4 mfma16(bf16x8 a, bf16x8 b, f32x4 c) {
  return __builtin_amdgcn_mfma_f32_16x16x32_bf16(a, b, c, 0, 0, 0);
}

__device__ __forceinline__ bf16x8 load8_f32_bf16(const float* p) {
  const float4 v0 = ((const float4*)p)[0];
  const float4 v1 = ((const float4*)p)[1];
  bf16x8 r;
  r[0] = f2bf(v0.x); r[1] = f2bf(v0.y); r[2] = f2bf(v0.z); r[3] = f2bf(v0.w);
  r[4] = f2bf(v1.x); r[5] = f2bf(v1.y); r[6] = f2bf(v1.z); r[7] = f2bf(v1.w);
  return r;
}

// ---------------- CSR build ----------------
__global__ __launch_bounds__(256) void hist_kernel(const int* __restrict__ ei,
                                                   int* __restrict__ hist) {
  int e = blockIdx.x * 256 + threadIdx.x;
  if (e < N_EDGES) atomicAdd(&hist[ei[N_EDGES + e]], 1);
}

__global__ __launch_bounds__(256) void scan1_kernel(const int* __restrict__ hist,
                                                    int* __restrict__ tmp,
                                                    int* __restrict__ bsum) {
  __shared__ int ls[256];
  const int t = threadIdx.x;
  const int i = blockIdx.x * 256 + t;
  int v = (i < N_NODES) ? hist[i] : 0;
  ls[t] = v;
  __syncthreads();
  for (int off = 1; off < 256; off <<= 1) {
    int u = (t >= off) ? ls[t - off] : 0;
    __syncthreads();
    ls[t] += u;
    __syncthreads();
  }
  if (i < N_NODES) tmp[i] = ls[t];
  if (t == 255) bsum[blockIdx.x] = ls[255];
}

__global__ __launch_bounds__(256) void scan2_kernel(const int* __restrict__ bsum,
                                                    int* __restrict__ bpfx,
                                                    int* __restrict__ row_start) {
  __shared__ int ls[256];
  const int t = threadIdx.x;
  int v = (t < NBLK_SCAN) ? bsum[t] : 0;
  ls[t] = v;
  __syncthreads();
  for (int off = 1; off < 256; off <<= 1) {
    int u = (t >= off) ? ls[t - off] : 0;
    __syncthreads();
    ls[t] += u;
    __syncthreads();
  }
  if (t < NBLK_SCAN) bpfx[t] = ls[t] - v;
  if (t == 255) row_start[N_NODES] = ls[255];
}

__global__ __launch_bounds__(256) void scan3_kernel(const int* __restrict__ hist,
                                                    const int* __restrict__ tmp,
                                                    const int* __restrict__ bpfx,
                                                    int* __restrict__ row_start,
                                                    int* __restrict__ cursor) {
  const int i = blockIdx.x * 256 + threadIdx.x;
  if (i < N_NODES) {
    int rs = tmp[i] - hist[i] + bpfx[blockIdx.x];
    row_start[i] = rs;
    cursor[i] = rs;
  }
}

// build dst-sorted (edge, src) pairs
__global__ __launch_bounds__(256) void perm_kernel(const int* __restrict__ ei,
                                                   int* __restrict__ cursor,
                                                   int2* __restrict__ epk) {
  int e = blockIdx.x * 256 + threadIdx.x;
  if (e < N_EDGES) {
    int dst = ei[N_EDGES + e];
    int pos = atomicAdd(&cursor[dst], 1);
    epk[pos] = make_int2(e, ei[e]);
  }
}

// ---------------- kernel 1: hb = bf16(x @ W_in), direct stores (R3-proven mapping) ----------------
__global__ __launch_bounds__(256) void hproj_kernel(
    const float* __restrict__ x, const float* __restrict__ W_in,
    unsigned short* __restrict__ hb)
{
  __shared__ __align__(16) unsigned short sWt[128 * 136];
  const int tid = threadIdx.x, wave = tid >> 6, lane = tid & 63;
  const int ln = lane & 15, grp = lane >> 4;
  const int r0 = blockIdx.x * 64;

  for (int idx = tid; idx < 128 * 128; idx += 256) {
    int k = idx >> 7, c = idx & 127;
    sWt[c * 136 + k] = f2bf(W_in[idx]);
  }
  __syncthreads();

  const size_t r = (size_t)r0 + wave * 16 + ln;
  f32x4 acc[8];
#pragma unroll
  for (int ct = 0; ct < 8; ++ct) acc[ct] = (f32x4){0.f, 0.f, 0.f, 0.f};
#pragma unroll
  for (int ks = 0; ks < 4; ++ks) {
    bf16x8 a = load8_f32_bf16(&x[r * 128 + ks * 32 + grp * 8]);
#pragma unroll
    for (int ct = 0; ct < 8; ++ct) {
      bf16x8 b = *(const bf16x8*)&sWt[(ct * 16 + ln) * 136 + ks * 32 + grp * 8];
      acc[ct] = mfma16(a, b, acc[ct]);
    }
  }
#pragma unroll
  for (int ct = 0; ct < 8; ++ct) {
#pragma unroll
    for (int i = 0; i < 4; ++i) {
      hb[(size_t)(r0 + wave * 16 + grp * 4 + i) * 128 + ct * 16 + ln] =
          (unsigned short)f2bf(acc[ct][i]);
    }
  }
}

// ---------------- kernel 2: Wf filter MLP — barrier-free wave-private loop, LDS weights ----------------
__global__ __launch_bounds__(256) void filt_kernel(
    const float* __restrict__ edge_attr,
    const float* __restrict__ edge_weight,
    const float* __restrict__ W_f1, const float* __restrict__ b_f1,
    const float* __restrict__ W_f2, const float* __restrict__ b_f2,
    unsigned short* __restrict__ Wf)
{
  __shared__ __align__(16) unsigned short sW1t[128 * 72];   // W1^T, K 50->64 zero-pad
  __shared__ __align__(16) unsigned short sW2t[128 * 136];  // W2^T
  __shared__ __align__(16) unsigned short sT[64 * 136];     // wave-private 16-row slabs
  __shared__ float sb1[128], sb2[128];

  const int tid = threadIdx.x, wave = tid >> 6, lane = tid & 63;
  const int ln = lane & 15, grp = lane >> 4;

  for (int idx = tid; idx < 128 * 64; idx += 256) {
    int k = idx >> 7, c = idx & 127;
    sW1t[c * 72 + k] = (k < NUM_RBF) ? f2bf(W_f1[k * 128 + c]) : (short)0;
  }
  for (int idx = tid; idx < 128 * 128; idx += 256) {
    int k = idx >> 7, c = idx & 127;
    sW2t[c * 136 + k] = f2bf(W_f2[idx]);
  }
  if (tid < 128) { sb1[tid] = b_f1[tid]; sb2[tid] = b_f2[tid]; }
  __syncthreads();  // the only barrier in the kernel

  const int gw = blockIdx.x * 4 + wave;     // global wave id
  const int nw = gridDim.x * 4;
  const int nChunks = N_EDGES / 16;         // 40000 chunks of 16 edges

  for (int chunk = gw; chunk < nChunks; chunk += nw) {
    const int e0 = chunk * 16;
    // ---- A-fragments direct from global (row = e0+ln, 200B stride, 8B aligned) ----
    const float* ap = edge_attr + (size_t)(e0 + ln) * NUM_RBF;
    bf16x8 a0, a1;
    {
      const float2* p = (const float2*)(ap + grp * 8);
      float2 v0 = p[0], v1 = p[1], v2 = p[2], v3 = p[3];
      a0[0] = f2bf(v0.x); a0[1] = f2bf(v0.y); a0[2] = f2bf(v1.x); a0[3] = f2bf(v1.y);
      a0[4] = f2bf(v2.x); a0[5] = f2bf(v2.y); a0[6] = f2bf(v3.x); a0[7] = f2bf(v3.y);
    }
    a1 = (bf16x8){0, 0, 0, 0, 0, 0, 0, 0};
    if (grp < 2) {
      const float2* p = (const float2*)(ap + 32 + grp * 8);
      float2 v0 = p[0], v1 = p[1], v2 = p[2], v3 = p[3];
      a1[0] = f2bf(v0.x); a1[1] = f2bf(v0.y); a1[2] = f2bf(v1.x); a1[3] = f2bf(v1.y);
      a1[4] = f2bf(v2.x); a1[5] = f2bf(v2.y); a1[6] = f2bf(v3.x); a1[7] = f2bf(v3.y);
    } else if (grp == 2) {
      const float2* p = (const float2*)(ap + 48);
      float2 v0 = p[0];
      a1[0] = f2bf(v0.x); a1[1] = f2bf(v0.y);
    }

    // ---- GEMM1: T = tanh(A @ W1 + b1) -> own 16-row slab ----
#pragma unroll
    for (int ct = 0; ct < 8; ++ct) {
      f32x4 z = {0.f, 0.f, 0.f, 0.f};
      int c = ct * 16 + ln;
      bf16x8 b0 = *(const bf16x8*)&sW1t[c * 72 + grp * 8];
      bf16x8 b1 = *(const bf16x8*)&sW1t[c * 72 + 32 + grp * 8];
      z = mfma16(a0, b0, z);
      z = mfma16(a1, b1, z);
      float bias = sb1[c];
#pragma unroll
      for (int i = 0; i < 4; ++i) {
        int rl = wave * 16 + grp * 4 + i;
        sT[rl * 136 + c] = (unsigned short)f2bf(fast_tanh(z[i] + bias));
      }
    }
    WAVE_FENCE();  // T short-writes ordered before vector reads (same wave)

    // ---- GEMM2: Wf = (T @ W2 + b2) * C ----
    bf16x8 af[4];
#pragma unroll
    for (int ks = 0; ks < 4; ++ks)
      af[ks] = *(const bf16x8*)&sT[(wave * 16 + ln) * 136 + ks * 32 + grp * 8];
    WAVE_FENCE();  // af reads complete before slab overwritten below
    float Cv[4];
#pragma unroll
    for (int i = 0; i < 4; ++i)
      Cv[i] = 0.5f * (__cosf(edge_weight[e0 + grp * 4 + i] * 0.31415926535f) + 1.0f);
#pragma unroll
    for (int ct = 0; ct < 8; ++ct) {
      f32x4 z = {0.f, 0.f, 0.f, 0.f};
      int c = ct * 16 + ln;
#pragma unroll
      for (int ks = 0; ks < 4; ++ks) {
        bf16x8 b = *(const bf16x8*)&sW2t[c * 136 + ks * 32 + grp * 8];
        z = mfma16(af[ks], b, z);
      }
      float bias = sb2[c];
#pragma unroll
      for (int i = 0; i < 4; ++i) {
        int rl = wave * 16 + grp * 4 + i;
        sT[rl * 136 + c] = (unsigned short)f2bf((z[i] + bias) * Cv[i]);
      }
    }
    WAVE_FENCE();  // Wf short-writes ordered before uint writeout reads

    // ---- coalesced contiguous writeout: own 16 rows x 256B ----
#pragma unroll
    for (int j = 0; j < 16; ++j) {
      ((unsigned int*)Wf)[(size_t)(e0 + j) * 64 + lane] =
          *(const unsigned int*)&sT[(wave * 16 + j) * 136 + lane * 2];
    }
    WAVE_FENCE();  // writeout reads done before next-iteration slab writes
  }
}

// ---------------- kernel 3: agg (f32, full d_out rows) = segment-sum(Wf[e] * h[src]) ----------------
__global__ __launch_bounds__(256) void gather_kernel(
    const int* __restrict__ row_start,
    const int2* __restrict__ epk,
    const unsigned int* __restrict__ Wf32,
    const unsigned int* __restrict__ hb32,
    float* __restrict__ aggf)   // = d_out, full f32 rows
{
  const int node = blockIdx.x * 4 + (threadIdx.x >> 6);
  const int lane = threadIdx.x & 63;
  int i = row_start[node];
  const int ee = row_start[node + 1];
  float ax = 0.f, ay = 0.f, bx = 0.f, by = 0.f;
  for (; i + 1 < ee; i += 2) {
    int2 p0 = epk[i];
    int2 p1 = epk[i + 1];
    unsigned int w0 = Wf32[(size_t)p0.x * 64 + lane];
    unsigned int h0 = hb32[(size_t)p0.y * 64 + lane];
    unsigned int w1 = Wf32[(size_t)p1.x * 64 + lane];
    unsigned int h1 = hb32[(size_t)p1.y * 64 + lane];
    ax = fmaf(bflo(w0), bflo(h0), ax);
    ay = fmaf(bfhi(w0), bfhi(h0), ay);
    bx = fmaf(bflo(w1), bflo(h1), bx);
    by = fmaf(bfhi(w1), bfhi(h1), by);
  }
  if (i < ee) {
    int2 p0 = epk[i];
    unsigned int w0 = Wf32[(size_t)p0.x * 64 + lane];
    unsigned int h0 = hb32[(size_t)p0.y * 64 + lane];
    ax = fmaf(bflo(w0), bflo(h0), ax);
    ay = fmaf(bfhi(w0), bfhi(h0), ay);
  }
  ((float2*)aggf)[(size_t)node * 64 + lane] = make_float2(ax + bx, ay + by);
}

// ---------------- kernel 4 (R3-proven): out = tanh(agg@W_out+b_out) @ W_lin + b_lin ----------------
// agg and out may alias (both = d_out): no __restrict__, block-local rows only.
__global__ __launch_bounds__(256) void tail_kernel(
    const float* agg,
    const float* __restrict__ W_out, const float* __restrict__ b_out,
    const float* __restrict__ W_lin, const float* __restrict__ b_lin,
    float* out)
{
  __shared__ __align__(16) unsigned short sWo[128 * 136];
  __shared__ __align__(16) unsigned short sWl[128 * 136];
  __shared__ __align__(16) unsigned short sT[64 * 136];
  __shared__ float sbo[128], sbl[128];
  const int tid = threadIdx.x, wave = tid >> 6, lane = tid & 63;
  const int ln = lane & 15, grp = lane >> 4;
  const int r0 = blockIdx.x * 64;

  for (int idx = tid; idx < 128 * 128; idx += 256) {
    int k = idx >> 7, c = idx & 127;
    sWo[c * 136 + k] = f2bf(W_out[idx]);
    sWl[c * 136 + k] = f2bf(W_lin[idx]);
  }
  if (tid < 128) { sbo[tid] = b_out[tid]; sbl[tid] = b_lin[tid]; }
  __syncthreads();

  const size_t r = (size_t)r0 + wave * 16 + ln;
  f32x4 acc[8];
#pragma unroll
  for (int ct = 0; ct < 8; ++ct) acc[ct] = (f32x4){0.f, 0.f, 0.f, 0.f};
#pragma unroll
  for (int ks = 0; ks < 4; ++ks) {
    bf16x8 a = load8_f32_bf16(&agg[r * 128 + ks * 32 + grp * 8]);
#pragma unroll
    for (int ct = 0; ct < 8; ++ct) {
      bf16x8 b = *(const bf16x8*)&sWo[(ct * 16 + ln) * 136 + ks * 32 + grp * 8];
      acc[ct] = mfma16(a, b, acc[ct]);
    }
  }
#pragma unroll
  for (int ct = 0; ct < 8; ++ct) {
    int c = ct * 16 + ln;
    float bias = sbo[c];
#pragma unroll
    for (int i = 0; i < 4; ++i) {
      int rl = wave * 16 + grp * 4 + i;
      sT[rl * 136 + c] = f2bf(fast_tanh(acc[ct][i] + bias));
    }
  }
  __syncthreads();

  bf16x8 af[4];
#pragma unroll
  for (int ks = 0; ks < 4; ++ks)
    af[ks] = *(const bf16x8*)&sT[(wave * 16 + ln) * 136 + ks * 32 + grp * 8];
  f32x4 acc2[8];
#pragma unroll
  for (int ct = 0; ct < 8; ++ct) {
    f32x4 z = {0.f, 0.f, 0.f, 0.f};
    int c = ct * 16 + ln;
#pragma unroll
    for (int ks = 0; ks < 4; ++ks) {
      bf16x8 b = *(const bf16x8*)&sWl[c * 136 + ks * 32 + grp * 8];
      z = mfma16(af[ks], b, z);
    }
    acc2[ct] = z;
  }
  __syncthreads();  // all agg reads done before overwriting rows
#pragma unroll
  for (int ct = 0; ct < 8; ++ct) {
    int c = ct * 16 + ln;
    float bias = sbl[c];
#pragma unroll
    for (int i = 0; i < 4; ++i) {
      out[(size_t)(r0 + wave * 16 + grp * 4 + i) * 128 + c] = acc2[ct][i] + bias;
    }
  }
}

// ================= fallback path (atomic, bf16 h) =================
__global__ __launch_bounds__(256, 2) void edge_kernel(
    const float* __restrict__ edge_attr,
    const int*   __restrict__ edge_index,
    const float* __restrict__ edge_weight,
    const float* __restrict__ W_f1, const float* __restrict__ b_f1,
    const float* __restrict__ W_f2, const float* __restrict__ b_f2,
    const unsigned short* __restrict__ hb, float* __restrict__ agg)
{
  __shared__ __align__(16) unsigned short sW1t[128 * 72];
  __shared__ __align__(16) unsigned short sW2t[128 * 136];
  __shared__ __align__(16) unsigned short sT[64 * 136];
  __shared__ float sb1[128], sb2[128], sC[64];
  __shared__ int sSrc[64], sDst[64];

  const int tid = threadIdx.x, wave = tid >> 6, lane = tid & 63;
  const int ln = lane & 15, grp = lane >> 4;

  for (int idx = tid; idx < 128 * 64; idx += 256) {
    int k = idx >> 7, c = idx & 127;
    sW1t[c * 72 + k] = (k < NUM_RBF) ? f2bf(W_f1[k * 128 + c]) : (short)0;
  }
  for (int idx = tid; idx < 128 * 128; idx += 256) {
    int k = idx >> 7, c = idx & 127;
    sW2t[c * 136 + k] = f2bf(W_f2[idx]);
  }
  if (tid < 128) { sb1[tid] = b_f1[tid]; sb2[tid] = b_f2[tid]; }

  const int nTiles = N_EDGES / 64;
  for (int tile = blockIdx.x; tile < nTiles; tile += gridDim.x) {
    const int e0 = tile * 64;
    for (int idx = tid; idx < 64 * NUM_RBF; idx += 256) {
      int e = idx / NUM_RBF, k = idx - e * NUM_RBF;
      sT[e * 136 + k] = f2bf(edge_attr[(size_t)e0 * NUM_RBF + idx]);
    }
    for (int idx = tid; idx < 64 * 14; idx += 256) {
      int e = idx / 14, k = NUM_RBF + (idx - (idx / 14) * 14);
      sT[e * 136 + k] = 0;
    }
    if (tid < 64) {
      int e = e0 + tid;
      sC[tid] = 0.5f * (__cosf(edge_weight[e] * 0.31415926535f) + 1.0f);
      sSrc[tid] = edge_index[e];
      sDst[tid] = edge_index[N_EDGES + e];
    }
    __syncthreads();

    const int erow = wave * 16 + ln;
    bf16x8 a0 = *(const bf16x8*)&sT[erow * 136 + grp * 8];
    bf16x8 a1 = *(const bf16x8*)&sT[erow * 136 + 32 + grp * 8];
    __syncthreads();

    f32x4 acc[8];
#pragma unroll
    for (int ct = 0; ct < 8; ++ct) {
      f32x4 z = {0.f, 0.f, 0.f, 0.f};
      int c = ct * 16 + ln;
      bf16x8 b0 = *(const bf16x8*)&sW1t[c * 72 + grp * 8];
      bf16x8 b1 = *(const bf16x8*)&sW1t[c * 72 + 32 + grp * 8];
      z = mfma16(a0, b0, z);
      z = mfma16(a1, b1, z);
      acc[ct] = z;
    }
#pragma unroll
    for (int ct = 0; ct < 8; ++ct) {
      int c = ct * 16 + ln;
      float bias = sb1[c];
#pragma unroll
      for (int i = 0; i < 4; ++i) {
        int el = wave * 16 + grp * 4 + i;
        sT[el * 136 + c] = f2bf(fast_tanh(acc[ct][i] + bias));
      }
    }
    __syncthreads();

    bf16x8 af[4];
#pragma unroll
    for (int ks = 0; ks < 4; ++ks)
      af[ks] = *(const bf16x8*)&sT[erow * 136 + ks * 32 + grp * 8];
    f32x4 acc2[8];
#pragma unroll
    for (int ct = 0; ct < 8; ++ct) {
      f32x4 z = {0.f, 0.f, 0.f, 0.f};
      int c = ct * 16 + ln;
#pragma unroll
      for (int ks = 0; ks < 4; ++ks) {
        bf16x8 b = *(const bf16x8*)&sW2t[c * 136 + ks * 32 + grp * 8];
        z = mfma16(af[ks], b, z);
      }
      acc2[ct] = z;
    }
#pragma unroll
    for (int ct = 0; ct < 8; ++ct) {
      int c = ct * 16 + ln;
      float bias = sb2[c];
#pragma unroll
      for (int i = 0; i < 4; ++i) {
        int el = wave * 16 + grp * 4 + i;
        float wf = (acc2[ct][i] + bias) * sC[el];
        float m = bf2f(hb[(size_t)sSrc[el] * 128 + c]) * wf;
        atomicAdd(&agg[(size_t)sDst[el] * 128 + c], m);
      }
    }
    __syncthreads();
  }
}

extern "C" void kernel_launch(void* const* d_in, const int* in_sizes, int n_in,
                              void* d_out, int out_size, void* d_ws, size_t ws_size,
                              hipStream_t stream) {
  const float* x     = (const float*)d_in[0];
  const int*   ei    = (const int*)d_in[1];
  const float* ew    = (const float*)d_in[2];
  const float* ea    = (const float*)d_in[3];
  const float* W_f1  = (const float*)d_in[4];
  const float* b_f1  = (const float*)d_in[5];
  const float* W_f2  = (const float*)d_in[6];
  const float* b_f2  = (const float*)d_in[7];
  const float* W_in  = (const float*)d_in[8];
  const float* W_out = (const float*)d_in[9];
  const float* b_out = (const float*)d_in[10];
  const float* W_lin = (const float*)d_in[11];
  const float* b_lin = (const float*)d_in[12];

  const size_t HB_B  = (size_t)N_NODES * HIDDEN * 2;    // 10.24 MB  bf16 h
  const size_t WF_B  = (size_t)N_EDGES * HIDDEN * 2;    // 163.84 MB bf16 Wf
  const size_t I_B   = (size_t)N_NODES * 4;             // 160 KB
  const size_t RS_B  = ((size_t)(N_NODES + 1) * 4 + 15) & ~(size_t)15;
  const size_t SB_B  = 1024;
  const size_t EPK_B = (size_t)N_EDGES * 8;             // 5.12 MB
  const size_t NEED = HB_B + WF_B + I_B + RS_B + I_B + I_B + SB_B + SB_B + EPK_B;

  char* ws = (char*)d_ws;
  unsigned short* hb = (unsigned short*)ws;

  if (ws_size >= NEED) {
    char* q = ws + HB_B;
    unsigned short* Wf = (unsigned short*)q;  q += WF_B;
    int* hist      = (int*)q;                 q += I_B;
    int* row_start = (int*)q;                 q += RS_B;
    int* cursor    = (int*)q;                 q += I_B;
    int* tmp       = (int*)q;                 q += I_B;
    int* bsum      = (int*)q;                 q += SB_B;
    int* bpfx      = (int*)q;                 q += SB_B;
    int2* epk      = (int2*)q;

    hipMemsetAsync(hist, 0, I_B, stream);
    hist_kernel<<<(N_EDGES + 255) / 256, 256, 0, stream>>>(ei, hist);
    scan1_kernel<<<NBLK_SCAN, 256, 0, stream>>>(hist, tmp, bsum);
    scan2_kernel<<<1, 256, 0, stream>>>(bsum, bpfx, row_start);
    scan3_kernel<<<NBLK_SCAN, 256, 0, stream>>>(hist, tmp, bpfx, row_start, cursor);
    perm_kernel<<<(N_EDGES + 255) / 256, 256, 0, stream>>>(ei, cursor, epk);
    hproj_kernel<<<N_NODES / 64, 256, 0, stream>>>(x, W_in, hb);
    filt_kernel<<<512, 256, 0, stream>>>(ea, ew, W_f1, b_f1, W_f2, b_f2, Wf);
    gather_kernel<<<N_NODES / 4, 256, 0, stream>>>(row_start, epk,
                                                   (const unsigned int*)Wf,
                                                   (const unsigned int*)hb,
                                                   (float*)d_out);
    tail_kernel<<<N_NODES / 64, 256, 0, stream>>>((const float*)d_out,
                                                  W_out, b_out, W_lin, b_lin,
                                                  (float*)d_out);
  } else {
    float* agg = (float*)(ws + HB_B);
    hipMemsetAsync(agg, 0, (size_t)N_NODES * HIDDEN * 4, stream);
    hproj_kernel<<<N_NODES / 64, 256, 0, stream>>>(x, W_in, hb);
    edge_kernel<<<512, 256, 0, stream>>>(ea, ei, ew, W_f1, b_f1, W_f2, b_f2, hb, agg);
    tail_kernel<<<N_NODES / 64, 256, 0, stream>>>(agg, W_out, b_out, W_lin, b_lin,
                                                  (float*)d_out);
  }
}

// Round 10
// 281.797 us; speedup vs baseline: 1.3416x; 1.0291x over previous
//
#include <hip/hip_runtime.h>
#include <hip/hip_bf16.h>

#define N_NODES 40000
#define N_EDGES 640000
#define HIDDEN  128
#define NUM_RBF 50
#define NBLK_SCAN 157  // ceil(40000/256)

typedef __attribute__((ext_vector_type(8))) short bf16x8;
typedef __attribute__((ext_vector_type(4))) float f32x4;

// zero-runtime compiler fence: orders LDS short-writes before differently-typed
// reads within a wave (TBAA otherwise allows reordering — the R4-R6 bug)
#define WAVE_FENCE() do { asm volatile("" ::: "memory"); \
                          __builtin_amdgcn_sched_barrier(0); } while (0)

__device__ __forceinline__ short f2bf(float f) {
  __hip_bfloat16 h = __float2bfloat16(f);
  return (short)__builtin_bit_cast(unsigned short, h);
}
__device__ __forceinline__ float bf2f(unsigned short u) {
  unsigned int v = ((unsigned int)u) << 16;
  return __builtin_bit_cast(float, v);
}
__device__ __forceinline__ float bflo(unsigned int u) {
  return __builtin_bit_cast(float, u << 16);
}
__device__ __forceinline__ float bfhi(unsigned int u) {
  return __builtin_bit_cast(float, u & 0xffff0000u);
}
__device__ __forceinline__ unsigned int pack2bf(float a, float b) {
  return (unsigned int)(unsigned short)f2bf(a) |
         ((unsigned int)(unsigned short)f2bf(b) << 16);
}

__device__ __forceinline__ float fast_tanh(float x) {
  float e = __expf(2.0f * x);
  return 1.0f - 2.0f * __builtin_amdgcn_rcpf(e + 1.0f);
}

__device__ __forceinline__ f32x4 mfma16(bf16x8 a, bf16x8 b, f32x4 c) {
  return __builtin_amdgcn_mfma_f32_16x16x32_bf16(a, b, c, 0, 0, 0);
}

__device__ __forceinline__ bf16x8 load8_f32_bf16(const float* p) {
  const float4 v0 = ((const float4*)p)[0];
  const float4 v1 = ((const float4*)p)[1];
  bf16x8 r;
  r[0] = f2bf(v0.x); r[1] = f2bf(v0.y); r[2] = f2bf(v0.z); r[3] = f2bf(v0.w);
  r[4] = f2bf(v1.x); r[5] = f2bf(v1.y); r[6] = f2bf(v1.z); r[7] = f2bf(v1.w);
  return r;
}

// ---------------- CSR build ----------------
__global__ __launch_bounds__(256) void hist_kernel(const int* __restrict__ ei,
                                                   int* __restrict__ hist) {
  int e = blockIdx.x * 256 + threadIdx.x;
  if (e < N_EDGES) atomicAdd(&hist[ei[N_EDGES + e]], 1);
}

__global__ __launch_bounds__(256) void scan1_kernel(const int* __restrict__ hist,
                                                    int* __restrict__ tmp,
                                                    int* __restrict__ bsum) {
  __shared__ int ls[256];
  const int t = threadIdx.x;
  const int i = blockIdx.x * 256 + t;
  int v = (i < N_NODES) ? hist[i] : 0;
  ls[t] = v;
  __syncthreads();
  for (int off = 1; off < 256; off <<= 1) {
    int u = (t >= off) ? ls[t - off] : 0;
    __syncthreads();
    ls[t] += u;
    __syncthreads();
  }
  if (i < N_NODES) tmp[i] = ls[t];
  if (t == 255) bsum[blockIdx.x] = ls[255];
}

__global__ __launch_bounds__(256) void scan2_kernel(const int* __restrict__ bsum,
                                                    int* __restrict__ bpfx,
                                                    int* __restrict__ row_start) {
  __shared__ int ls[256];
  const int t = threadIdx.x;
  int v = (t < NBLK_SCAN) ? bsum[t] : 0;
  ls[t] = v;
  __syncthreads();
  for (int off = 1; off < 256; off <<= 1) {
    int u = (t >= off) ? ls[t - off] : 0;
    __syncthreads();
    ls[t] += u;
    __syncthreads();
  }
  if (t < NBLK_SCAN) bpfx[t] = ls[t] - v;
  if (t == 255) row_start[N_NODES] = ls[255];
}

__global__ __launch_bounds__(256) void scan3_kernel(const int* __restrict__ hist,
                                                    const int* __restrict__ tmp,
                                                    const int* __restrict__ bpfx,
                                                    int* __restrict__ row_start,
                                                    int* __restrict__ cursor) {
  const int i = blockIdx.x * 256 + threadIdx.x;
  if (i < N_NODES) {
    int rs = tmp[i] - hist[i] + bpfx[blockIdx.x];
    row_start[i] = rs;
    cursor[i] = rs;
  }
}

// posOf[e] = dst-sorted slot of edge e
__global__ __launch_bounds__(256) void perm_kernel(const int* __restrict__ ei,
                                                   int* __restrict__ cursor,
                                                   int* __restrict__ posOf) {
  int e = blockIdx.x * 256 + threadIdx.x;
  if (e < N_EDGES) {
    int dst = ei[N_EDGES + e];
    posOf[e] = atomicAdd(&cursor[dst], 1);
  }
}

// ---------------- kernel 1: hb = bf16(x @ W_in), direct stores (R3-proven mapping) ----------------
__global__ __launch_bounds__(256) void hproj_kernel(
    const float* __restrict__ x, const float* __restrict__ W_in,
    unsigned short* __restrict__ hb)
{
  __shared__ __align__(16) unsigned short sWt[128 * 136];
  const int tid = threadIdx.x, wave = tid >> 6, lane = tid & 63;
  const int ln = lane & 15, grp = lane >> 4;
  const int r0 = blockIdx.x * 64;

  for (int idx = tid; idx < 128 * 128; idx += 256) {
    int k = idx >> 7, c = idx & 127;
    sWt[c * 136 + k] = f2bf(W_in[idx]);
  }
  __syncthreads();

  const size_t r = (size_t)r0 + wave * 16 + ln;
  f32x4 acc[8];
#pragma unroll
  for (int ct = 0; ct < 8; ++ct) acc[ct] = (f32x4){0.f, 0.f, 0.f, 0.f};
#pragma unroll
  for (int ks = 0; ks < 4; ++ks) {
    bf16x8 a = load8_f32_bf16(&x[r * 128 + ks * 32 + grp * 8]);
#pragma unroll
    for (int ct = 0; ct < 8; ++ct) {
      bf16x8 b = *(const bf16x8*)&sWt[(ct * 16 + ln) * 136 + ks * 32 + grp * 8];
      acc[ct] = mfma16(a, b, acc[ct]);
    }
  }
#pragma unroll
  for (int ct = 0; ct < 8; ++ct) {
#pragma unroll
    for (int i = 0; i < 4; ++i) {
      hb[(size_t)(r0 + wave * 16 + grp * 4 + i) * 128 + ct * 16 + ln] =
          (unsigned short)f2bf(acc[ct][i]);
    }
  }
}

// ---------------- kernel 2: filter MLP + h-gather -> dst-sorted msg rows (barrier-free loop) ----------------
__global__ __launch_bounds__(256) void filt_kernel(
    const float* __restrict__ edge_attr,
    const float* __restrict__ edge_weight,
    const int*   __restrict__ ei,
    const int*   __restrict__ posOf,
    const unsigned int* __restrict__ hb32,
    const float* __restrict__ W_f1, const float* __restrict__ b_f1,
    const float* __restrict__ W_f2, const float* __restrict__ b_f2,
    unsigned int* __restrict__ msg32)
{
  __shared__ __align__(16) unsigned short sW1t[128 * 72];   // W1^T, K 50->64 zero-pad
  __shared__ __align__(16) unsigned short sW2t[128 * 136];  // W2^T
  __shared__ __align__(16) unsigned short sT[64 * 136];     // wave-private 16-row slabs
  __shared__ float sb1[128], sb2[128];

  const int tid = threadIdx.x, wave = tid >> 6, lane = tid & 63;
  const int ln = lane & 15, grp = lane >> 4;

  for (int idx = tid; idx < 128 * 64; idx += 256) {
    int k = idx >> 7, c = idx & 127;
    sW1t[c * 72 + k] = (k < NUM_RBF) ? f2bf(W_f1[k * 128 + c]) : (short)0;
  }
  for (int idx = tid; idx < 128 * 128; idx += 256) {
    int k = idx >> 7, c = idx & 127;
    sW2t[c * 136 + k] = f2bf(W_f2[idx]);
  }
  if (tid < 128) { sb1[tid] = b_f1[tid]; sb2[tid] = b_f2[tid]; }
  __syncthreads();  // the only barrier in the kernel

  const int gw = blockIdx.x * 4 + wave;     // global wave id
  const int nw = gridDim.x * 4;
  const int nChunks = N_EDGES / 16;         // 40000 chunks of 16 edges

  for (int chunk = gw; chunk < nChunks; chunk += nw) {
    const int e0 = chunk * 16;
    // ---- A-fragments direct from global (row = e0+ln, 200B stride, 8B aligned) ----
    const float* ap = edge_attr + (size_t)(e0 + ln) * NUM_RBF;
    bf16x8 a0, a1;
    {
      const float2* p = (const float2*)(ap + grp * 8);
      float2 v0 = p[0], v1 = p[1], v2 = p[2], v3 = p[3];
      a0[0] = f2bf(v0.x); a0[1] = f2bf(v0.y); a0[2] = f2bf(v1.x); a0[3] = f2bf(v1.y);
      a0[4] = f2bf(v2.x); a0[5] = f2bf(v2.y); a0[6] = f2bf(v3.x); a0[7] = f2bf(v3.y);
    }
    a1 = (bf16x8){0, 0, 0, 0, 0, 0, 0, 0};
    if (grp < 2) {
      const float2* p = (const float2*)(ap + 32 + grp * 8);
      float2 v0 = p[0], v1 = p[1], v2 = p[2], v3 = p[3];
      a1[0] = f2bf(v0.x); a1[1] = f2bf(v0.y); a1[2] = f2bf(v1.x); a1[3] = f2bf(v1.y);
      a1[4] = f2bf(v2.x); a1[5] = f2bf(v2.y); a1[6] = f2bf(v3.x); a1[7] = f2bf(v3.y);
    } else if (grp == 2) {
      const float2* p = (const float2*)(ap + 48);
      float2 v0 = p[0];
      a1[0] = f2bf(v0.x); a1[1] = f2bf(v0.y);
    }

    // ---- GEMM1: T = tanh(A @ W1 + b1) -> own 16-row slab ----
#pragma unroll
    for (int ct = 0; ct < 8; ++ct) {
      f32x4 z = {0.f, 0.f, 0.f, 0.f};
      int c = ct * 16 + ln;
      bf16x8 b0 = *(const bf16x8*)&sW1t[c * 72 + grp * 8];
      bf16x8 b1 = *(const bf16x8*)&sW1t[c * 72 + 32 + grp * 8];
      z = mfma16(a0, b0, z);
      z = mfma16(a1, b1, z);
      float bias = sb1[c];
#pragma unroll
      for (int i = 0; i < 4; ++i) {
        int rl = wave * 16 + grp * 4 + i;
        sT[rl * 136 + c] = (unsigned short)f2bf(fast_tanh(z[i] + bias));
      }
    }
    WAVE_FENCE();  // T short-writes ordered before vector reads (same wave)

    // ---- GEMM2: Wf = (T @ W2 + b2) * C ----
    bf16x8 af[4];
#pragma unroll
    for (int ks = 0; ks < 4; ++ks)
      af[ks] = *(const bf16x8*)&sT[(wave * 16 + ln) * 136 + ks * 32 + grp * 8];
    WAVE_FENCE();  // af reads complete before slab overwritten below
    float Cv[4];
#pragma unroll
    for (int i = 0; i < 4; ++i)
      Cv[i] = 0.5f * (__cosf(edge_weight[e0 + grp * 4 + i] * 0.31415926535f) + 1.0f);
#pragma unroll
    for (int ct = 0; ct < 8; ++ct) {
      f32x4 z = {0.f, 0.f, 0.f, 0.f};
      int c = ct * 16 + ln;
#pragma unroll
      for (int ks = 0; ks < 4; ++ks) {
        bf16x8 b = *(const bf16x8*)&sW2t[c * 136 + ks * 32 + grp * 8];
        z = mfma16(af[ks], b, z);
      }
      float bias = sb2[c];
#pragma unroll
      for (int i = 0; i < 4; ++i) {
        int rl = wave * 16 + grp * 4 + i;
        sT[rl * 136 + c] = (unsigned short)f2bf((z[i] + bias) * Cv[i]);
      }
    }
    WAVE_FENCE();  // Wf short-writes ordered before uint writeout reads

    // ---- gather h row, multiply, write msg row at dst-sorted slot (256B, latency-free store) ----
#pragma unroll
    for (int j = 0; j < 16; ++j) {
      int e = e0 + j;
      int src = ei[e];          // wave-uniform scalar loads
      int pos = posOf[e];
      unsigned int hv = hb32[(size_t)src * 64 + lane];
      unsigned int w = *(const unsigned int*)&sT[(wave * 16 + j) * 136 + lane * 2];
      msg32[(size_t)pos * 64 + lane] =
          pack2bf(bflo(w) * bflo(hv), bfhi(w) * bfhi(hv));
    }
    WAVE_FENCE();  // writeout reads done before next-iteration slab writes
  }
}

// ---------------- kernel 3: agg (f32, d_out rows) = segment-sum over CONTIGUOUS msg rows ----------------
__global__ __launch_bounds__(256) void segsum_kernel(
    const int* __restrict__ row_start,
    const unsigned int* __restrict__ msg32,
    float* __restrict__ aggf)   // = d_out, full f32 rows
{
  const int node = blockIdx.x * 4 + (threadIdx.x >> 6);
  const int lane = threadIdx.x & 63;
  const int eb = row_start[node], ee = row_start[node + 1];
  const int n = ee - eb;
  const unsigned int* p = msg32 + (size_t)eb * 64 + lane;
  float ax = 0.f, ay = 0.f, bx = 0.f, by = 0.f;
  int k = 0;
  for (; k + 1 < n; k += 2) {
    unsigned int u0 = p[(size_t)k * 64];
    unsigned int u1 = p[(size_t)(k + 1) * 64];
    ax += bflo(u0); ay += bfhi(u0);
    bx += bflo(u1); by += bfhi(u1);
  }
  if (k < n) {
    unsigned int u0 = p[(size_t)k * 64];
    ax += bflo(u0); ay += bfhi(u0);
  }
  ((float2*)aggf)[(size_t)node * 64 + lane] = make_float2(ax + bx, ay + by);
}

// ---------------- kernel 4 (R3-proven): out = tanh(agg@W_out+b_out) @ W_lin + b_lin ----------------
// agg and out may alias (both = d_out): no __restrict__, block-local rows only.
__global__ __launch_bounds__(256) void tail_kernel(
    const float* agg,
    const float* __restrict__ W_out, const float* __restrict__ b_out,
    const float* __restrict__ W_lin, const float* __restrict__ b_lin,
    float* out)
{
  __shared__ __align__(16) unsigned short sWo[128 * 136];
  __shared__ __align__(16) unsigned short sWl[128 * 136];
  __shared__ __align__(16) unsigned short sT[64 * 136];
  __shared__ float sbo[128], sbl[128];
  const int tid = threadIdx.x, wave = tid >> 6, lane = tid & 63;
  const int ln = lane & 15, grp = lane >> 4;
  const int r0 = blockIdx.x * 64;

  for (int idx = tid; idx < 128 * 128; idx += 256) {
    int k = idx >> 7, c = idx & 127;
    sWo[c * 136 + k] = f2bf(W_out[idx]);
    sWl[c * 136 + k] = f2bf(W_lin[idx]);
  }
  if (tid < 128) { sbo[tid] = b_out[tid]; sbl[tid] = b_lin[tid]; }
  __syncthreads();

  const size_t r = (size_t)r0 + wave * 16 + ln;
  f32x4 acc[8];
#pragma unroll
  for (int ct = 0; ct < 8; ++ct) acc[ct] = (f32x4){0.f, 0.f, 0.f, 0.f};
#pragma unroll
  for (int ks = 0; ks < 4; ++ks) {
    bf16x8 a = load8_f32_bf16(&agg[r * 128 + ks * 32 + grp * 8]);
#pragma unroll
    for (int ct = 0; ct < 8; ++ct) {
      bf16x8 b = *(const bf16x8*)&sWo[(ct * 16 + ln) * 136 + ks * 32 + grp * 8];
      acc[ct] = mfma16(a, b, acc[ct]);
    }
  }
#pragma unroll
  for (int ct = 0; ct < 8; ++ct) {
    int c = ct * 16 + ln;
    float bias = sbo[c];
#pragma unroll
    for (int i = 0; i < 4; ++i) {
      int rl = wave * 16 + grp * 4 + i;
      sT[rl * 136 + c] = f2bf(fast_tanh(acc[ct][i] + bias));
    }
  }
  __syncthreads();

  bf16x8 af[4];
#pragma unroll
  for (int ks = 0; ks < 4; ++ks)
    af[ks] = *(const bf16x8*)&sT[(wave * 16 + ln) * 136 + ks * 32 + grp * 8];
  f32x4 acc2[8];
#pragma unroll
  for (int ct = 0; ct < 8; ++ct) {
    f32x4 z = {0.f, 0.f, 0.f, 0.f};
    int c = ct * 16 + ln;
#pragma unroll
    for (int ks = 0; ks < 4; ++ks) {
      bf16x8 b = *(const bf16x8*)&sWl[c * 136 + ks * 32 + grp * 8];
      z = mfma16(af[ks], b, z);
    }
    acc2[ct] = z;
  }
  __syncthreads();  // all agg reads done before overwriting rows
#pragma unroll
  for (int ct = 0; ct < 8; ++ct) {
    int c = ct * 16 + ln;
    float bias = sbl[c];
#pragma unroll
    for (int i = 0; i < 4; ++i) {
      out[(size_t)(r0 + wave * 16 + grp * 4 + i) * 128 + c] = acc2[ct][i] + bias;
    }
  }
}

// ================= fallback path (atomic, bf16 h) =================
__global__ __launch_bounds__(256, 2) void edge_kernel(
    const float* __restrict__ edge_attr,
    const int*   __restrict__ edge_index,
    const float* __restrict__ edge_weight,
    const float* __restrict__ W_f1, const float* __restrict__ b_f1,
    const float* __restrict__ W_f2, const float* __restrict__ b_f2,
    const unsigned short* __restrict__ hb, float* __restrict__ agg)
{
  __shared__ __align__(16) unsigned short sW1t[128 * 72];
  __shared__ __align__(16) unsigned short sW2t[128 * 136];
  __shared__ __align__(16) unsigned short sT[64 * 136];
  __shared__ float sb1[128], sb2[128], sC[64];
  __shared__ int sSrc[64], sDst[64];

  const int tid = threadIdx.x, wave = tid >> 6, lane = tid & 63;
  const int ln = lane & 15, grp = lane >> 4;

  for (int idx = tid; idx < 128 * 64; idx += 256) {
    int k = idx >> 7, c = idx & 127;
    sW1t[c * 72 + k] = (k < NUM_RBF) ? f2bf(W_f1[k * 128 + c]) : (short)0;
  }
  for (int idx = tid; idx < 128 * 128; idx += 256) {
    int k = idx >> 7, c = idx & 127;
    sW2t[c * 136 + k] = f2bf(W_f2[idx]);
  }
  if (tid < 128) { sb1[tid] = b_f1[tid]; sb2[tid] = b_f2[tid]; }

  const int nTiles = N_EDGES / 64;
  for (int tile = blockIdx.x; tile < nTiles; tile += gridDim.x) {
    const int e0 = tile * 64;
    for (int idx = tid; idx < 64 * NUM_RBF; idx += 256) {
      int e = idx / NUM_RBF, k = idx - e * NUM_RBF;
      sT[e * 136 + k] = f2bf(edge_attr[(size_t)e0 * NUM_RBF + idx]);
    }
    for (int idx = tid; idx < 64 * 14; idx += 256) {
      int e = idx / 14, k = NUM_RBF + (idx - (idx / 14) * 14);
      sT[e * 136 + k] = 0;
    }
    if (tid < 64) {
      int e = e0 + tid;
      sC[tid] = 0.5f * (__cosf(edge_weight[e] * 0.31415926535f) + 1.0f);
      sSrc[tid] = edge_index[e];
      sDst[tid] = edge_index[N_EDGES + e];
    }
    __syncthreads();

    const int erow = wave * 16 + ln;
    bf16x8 a0 = *(const bf16x8*)&sT[erow * 136 + grp * 8];
    bf16x8 a1 = *(const bf16x8*)&sT[erow * 136 + 32 + grp * 8];
    __syncthreads();

    f32x4 acc[8];
#pragma unroll
    for (int ct = 0; ct < 8; ++ct) {
      f32x4 z = {0.f, 0.f, 0.f, 0.f};
      int c = ct * 16 + ln;
      bf16x8 b0 = *(const bf16x8*)&sW1t[c * 72 + grp * 8];
      bf16x8 b1 = *(const bf16x8*)&sW1t[c * 72 + 32 + grp * 8];
      z = mfma16(a0, b0, z);
      z = mfma16(a1, b1, z);
      acc[ct] = z;
    }
#pragma unroll
    for (int ct = 0; ct < 8; ++ct) {
      int c = ct * 16 + ln;
      float bias = sb1[c];
#pragma unroll
      for (int i = 0; i < 4; ++i) {
        int el = wave * 16 + grp * 4 + i;
        sT[el * 136 + c] = f2bf(fast_tanh(acc[ct][i] + bias));
      }
    }
    __syncthreads();

    bf16x8 af[4];
#pragma unroll
    for (int ks = 0; ks < 4; ++ks)
      af[ks] = *(const bf16x8*)&sT[erow * 136 + ks * 32 + grp * 8];
    f32x4 acc2[8];
#pragma unroll
    for (int ct = 0; ct < 8; ++ct) {
      f32x4 z = {0.f, 0.f, 0.f, 0.f};
      int c = ct * 16 + ln;
#pragma unroll
      for (int ks = 0; ks < 4; ++ks) {
        bf16x8 b = *(const bf16x8*)&sW2t[c * 136 + ks * 32 + grp * 8];
        z = mfma16(af[ks], b, z);
      }
      acc2[ct] = z;
    }
#pragma unroll
    for (int ct = 0; ct < 8; ++ct) {
      int c = ct * 16 + ln;
      float bias = sb2[c];
#pragma unroll
      for (int i = 0; i < 4; ++i) {
        int el = wave * 16 + grp * 4 + i;
        float wf = (acc2[ct][i] + bias) * sC[el];
        float m = bf2f(hb[(size_t)sSrc[el] * 128 + c]) * wf;
        atomicAdd(&agg[(size_t)sDst[el] * 128 + c], m);
      }
    }
    __syncthreads();
  }
}

extern "C" void kernel_launch(void* const* d_in, const int* in_sizes, int n_in,
                              void* d_out, int out_size, void* d_ws, size_t ws_size,
                              hipStream_t stream) {
  const float* x     = (const float*)d_in[0];
  const int*   ei    = (const int*)d_in[1];
  const float* ew    = (const float*)d_in[2];
  const float* ea    = (const float*)d_in[3];
  const float* W_f1  = (const float*)d_in[4];
  const float* b_f1  = (const float*)d_in[5];
  const float* W_f2  = (const float*)d_in[6];
  const float* b_f2  = (const float*)d_in[7];
  const float* W_in  = (const float*)d_in[8];
  const float* W_out = (const float*)d_in[9];
  const float* b_out = (const float*)d_in[10];
  const float* W_lin = (const float*)d_in[11];
  const float* b_lin = (const float*)d_in[12];

  const size_t HB_B  = (size_t)N_NODES * HIDDEN * 2;    // 10.24 MB  bf16 h
  const size_t MSG_B = (size_t)N_EDGES * HIDDEN * 2;    // 163.84 MB bf16 msg
  const size_t I_B   = (size_t)N_NODES * 4;             // 160 KB
  const size_t RS_B  = ((size_t)(N_NODES + 1) * 4 + 15) & ~(size_t)15;
  const size_t SB_B  = 1024;
  const size_t POS_B = (size_t)N_EDGES * 4;             // 2.56 MB
  const size_t NEED = HB_B + MSG_B + I_B + RS_B + I_B + I_B + SB_B + SB_B + POS_B;

  char* ws = (char*)d_ws;
  unsigned short* hb = (unsigned short*)ws;

  if (ws_size >= NEED) {
    char* q = ws + HB_B;
    unsigned short* msg = (unsigned short*)q;  q += MSG_B;
    int* hist      = (int*)q;                  q += I_B;
    int* row_start = (int*)q;                  q += RS_B;
    int* cursor    = (int*)q;                  q += I_B;
    int* tmp       = (int*)q;                  q += I_B;
    int* bsum      = (int*)q;                  q += SB_B;
    int* bpfx      = (int*)q;                  q += SB_B;
    int* posOf     = (int*)q;

    hipMemsetAsync(hist, 0, I_B, stream);
    hist_kernel<<<(N_EDGES + 255) / 256, 256, 0, stream>>>(ei, hist);
    scan1_kernel<<<NBLK_SCAN, 256, 0, stream>>>(hist, tmp, bsum);
    scan2_kernel<<<1, 256, 0, stream>>>(bsum, bpfx, row_start);
    scan3_kernel<<<NBLK_SCAN, 256, 0, stream>>>(hist, tmp, bpfx, row_start, cursor);
    perm_kernel<<<(N_EDGES + 255) / 256, 256, 0, stream>>>(ei, cursor, posOf);
    hproj_kernel<<<N_NODES / 64, 256, 0, stream>>>(x, W_in, hb);
    filt_kernel<<<512, 256, 0, stream>>>(ea, ew, ei, posOf,
                                         (const unsigned int*)hb,
                                         W_f1, b_f1, W_f2, b_f2,
                                         (unsigned int*)msg);
    segsum_kernel<<<N_NODES / 4, 256, 0, stream>>>(row_start,
                                                   (const unsigned int*)msg,
                                                   (float*)d_out);
    tail_kernel<<<N_NODES / 64, 256, 0, stream>>>((const float*)d_out,
                                                  W_out, b_out, W_lin, b_lin,
                                                  (float*)d_out);
  } else {
    float* agg = (float*)(ws + HB_B);
    hipMemsetAsync(agg, 0, (size_t)N_NODES * HIDDEN * 4, stream);
    hproj_kernel<<<N_NODES / 64, 256, 0, stream>>>(x, W_in, hb);
    edge_kernel<<<512, 256, 0, stream>>>(ea, ei, ew, W_f1, b_f1, W_f2, b_f2, hb, agg);
    tail_kernel<<<N_NODES / 64, 256, 0, stream>>>(agg, W_out, b_out, W_lin, b_lin,
                                                  (float*)d_out);
  }
}

// Round 11
// 239.192 us; speedup vs baseline: 1.5806x; 1.1781x over previous
//
#include <hip/hip_runtime.h>
#include <hip/hip_bf16.h>

#define N_NODES 40000
#define N_EDGES 640000
#define HIDDEN  128
#define NUM_RBF 50
#define NBLK_SCAN 157  // ceil(40000/256)

typedef __attribute__((ext_vector_type(8))) short bf16x8;
typedef __attribute__((ext_vector_type(4))) float f32x4;

// zero-runtime compiler fence: orders LDS short-writes before differently-typed
// reads within a wave (TBAA otherwise allows reordering — the R4-R6 bug)
#define WAVE_FENCE() do { asm volatile("" ::: "memory"); \
                          __builtin_amdgcn_sched_barrier(0); } while (0)

__device__ __forceinline__ short f2bf(float f) {
  __hip_bfloat16 h = __float2bfloat16(f);
  return (short)__builtin_bit_cast(unsigned short, h);
}
__device__ __forceinline__ float bf2f(unsigned short u) {
  unsigned int v = ((unsigned int)u) << 16;
  return __builtin_bit_cast(float, v);
}
__device__ __forceinline__ float bflo(unsigned int u) {
  return __builtin_bit_cast(float, u << 16);
}
__device__ __forceinline__ float bfhi(unsigned int u) {
  return __builtin_bit_cast(float, u & 0xffff0000u);
}
__device__ __forceinline__ unsigned int pack2bf(float a, float b) {
  return (unsigned int)(unsigned short)f2bf(a) |
         ((unsigned int)(unsigned short)f2bf(b) << 16);
}

__device__ __forceinline__ float fast_tanh(float x) {
  float e = __expf(2.0f * x);
  return 1.0f - 2.0f * __builtin_amdgcn_rcpf(e + 1.0f);
}

__device__ __forceinline__ f32x4 mfma16(bf16x8 a, bf16x8 b, f32x4 c) {
  return __builtin_amdgcn_mfma_f32_16x16x32_bf16(a, b, c, 0, 0, 0);
}

__device__ __forceinline__ bf16x8 load8_f32_bf16(const float* p) {
  const float4 v0 = ((const float4*)p)[0];
  const float4 v1 = ((const float4*)p)[1];
  bf16x8 r;
  r[0] = f2bf(v0.x); r[1] = f2bf(v0.y); r[2] = f2bf(v0.z); r[3] = f2bf(v0.w);
  r[4] = f2bf(v1.x); r[5] = f2bf(v1.y); r[6] = f2bf(v1.z); r[7] = f2bf(v1.w);
  return r;
}

// ---------------- CSR build ----------------
__global__ __launch_bounds__(256) void hist_kernel(const int* __restrict__ ei,
                                                   int* __restrict__ hist) {
  int e = blockIdx.x * 256 + threadIdx.x;
  if (e < N_EDGES) atomicAdd(&hist[ei[N_EDGES + e]], 1);
}

__global__ __launch_bounds__(256) void scan1_kernel(const int* __restrict__ hist,
                                                    int* __restrict__ tmp,
                                                    int* __restrict__ bsum) {
  __shared__ int ls[256];
  const int t = threadIdx.x;
  const int i = blockIdx.x * 256 + t;
  int v = (i < N_NODES) ? hist[i] : 0;
  ls[t] = v;
  __syncthreads();
  for (int off = 1; off < 256; off <<= 1) {
    int u = (t >= off) ? ls[t - off] : 0;
    __syncthreads();
    ls[t] += u;
    __syncthreads();
  }
  if (i < N_NODES) tmp[i] = ls[t];
  if (t == 255) bsum[blockIdx.x] = ls[255];
}

__global__ __launch_bounds__(256) void scan2_kernel(const int* __restrict__ bsum,
                                                    int* __restrict__ bpfx,
                                                    int* __restrict__ row_start) {
  __shared__ int ls[256];
  const int t = threadIdx.x;
  int v = (t < NBLK_SCAN) ? bsum[t] : 0;
  ls[t] = v;
  __syncthreads();
  for (int off = 1; off < 256; off <<= 1) {
    int u = (t >= off) ? ls[t - off] : 0;
    __syncthreads();
    ls[t] += u;
    __syncthreads();
  }
  if (t < NBLK_SCAN) bpfx[t] = ls[t] - v;
  if (t == 255) row_start[N_NODES] = ls[255];
}

__global__ __launch_bounds__(256) void scan3_kernel(const int* __restrict__ hist,
                                                    const int* __restrict__ tmp,
                                                    const int* __restrict__ bpfx,
                                                    int* __restrict__ row_start,
                                                    int* __restrict__ cursor) {
  const int i = blockIdx.x * 256 + threadIdx.x;
  if (i < N_NODES) {
    int rs = tmp[i] - hist[i] + bpfx[blockIdx.x];
    row_start[i] = rs;
    cursor[i] = rs;
  }
}

// posOf[e] = dst-sorted slot of edge e
__global__ __launch_bounds__(256) void perm_kernel(const int* __restrict__ ei,
                                                   int* __restrict__ cursor,
                                                   int* __restrict__ posOf) {
  int e = blockIdx.x * 256 + threadIdx.x;
  if (e < N_EDGES) {
    int dst = ei[N_EDGES + e];
    posOf[e] = atomicAdd(&cursor[dst], 1);
  }
}

// ---------------- kernel 1: hb = bf16(x @ W_in), direct stores (R3-proven mapping) ----------------
__global__ __launch_bounds__(256) void hproj_kernel(
    const float* __restrict__ x, const float* __restrict__ W_in,
    unsigned short* __restrict__ hb)
{
  __shared__ __align__(16) unsigned short sWt[128 * 136];
  const int tid = threadIdx.x, wave = tid >> 6, lane = tid & 63;
  const int ln = lane & 15, grp = lane >> 4;
  const int r0 = blockIdx.x * 64;

  for (int idx = tid; idx < 128 * 128; idx += 256) {
    int k = idx >> 7, c = idx & 127;
    sWt[c * 136 + k] = f2bf(W_in[idx]);
  }
  __syncthreads();

  const size_t r = (size_t)r0 + wave * 16 + ln;
  f32x4 acc[8];
#pragma unroll
  for (int ct = 0; ct < 8; ++ct) acc[ct] = (f32x4){0.f, 0.f, 0.f, 0.f};
#pragma unroll
  for (int ks = 0; ks < 4; ++ks) {
    bf16x8 a = load8_f32_bf16(&x[r * 128 + ks * 32 + grp * 8]);
#pragma unroll
    for (int ct = 0; ct < 8; ++ct) {
      bf16x8 b = *(const bf16x8*)&sWt[(ct * 16 + ln) * 136 + ks * 32 + grp * 8];
      acc[ct] = mfma16(a, b, acc[ct]);
    }
  }
#pragma unroll
  for (int ct = 0; ct < 8; ++ct) {
#pragma unroll
    for (int i = 0; i < 4; ++i) {
      hb[(size_t)(r0 + wave * 16 + grp * 4 + i) * 128 + ct * 16 + ln] =
          (unsigned short)f2bf(acc[ct][i]);
    }
  }
}

// ---------------- kernel 2: filter MLP + h-gather -> dst-sorted msg rows ----------------
// 1024 threads (16 waves) per block, ONE block per CU: weights shared by 16 waves,
// LDS ~121 KB, occupancy 16 waves/CU (4/SIMD) vs R10's 8. Barrier-free main loop.
__global__ __launch_bounds__(1024) void filt_kernel(
    const float* __restrict__ edge_attr,
    const float* __restrict__ edge_weight,
    const int*   __restrict__ ei,
    const int*   __restrict__ posOf,
    const unsigned int* __restrict__ hb32,
    const float* __restrict__ W_f1, const float* __restrict__ b_f1,
    const float* __restrict__ W_f2, const float* __restrict__ b_f2,
    unsigned int* __restrict__ msg32)
{
  __shared__ __align__(16) unsigned short sW1t[128 * 72];    // 18.4 KB
  __shared__ __align__(16) unsigned short sW2t[128 * 136];   // 34.8 KB
  __shared__ __align__(16) unsigned short sT[256 * 136];     // 69.6 KB: 16 wave-slabs
  __shared__ float sb1[128], sb2[128];

  const int tid = threadIdx.x, wave = tid >> 6, lane = tid & 63;
  const int ln = lane & 15, grp = lane >> 4;

  for (int idx = tid; idx < 128 * 64; idx += 1024) {
    int k = idx >> 7, c = idx & 127;
    sW1t[c * 72 + k] = (k < NUM_RBF) ? f2bf(W_f1[k * 128 + c]) : (short)0;
  }
  for (int idx = tid; idx < 128 * 128; idx += 1024) {
    int k = idx >> 7, c = idx & 127;
    sW2t[c * 136 + k] = f2bf(W_f2[idx]);
  }
  if (tid < 128) { sb1[tid] = b_f1[tid]; sb2[tid] = b_f2[tid]; }
  __syncthreads();  // the only barrier in the kernel

  const int gw = blockIdx.x * 16 + wave;    // global wave id
  const int nw = gridDim.x * 16;
  const int nChunks = N_EDGES / 16;         // 40000 chunks of 16 edges

  for (int chunk = gw; chunk < nChunks; chunk += nw) {
    const int e0 = chunk * 16;

    // ---- prefetch: indices + h rows issued FIRST, latency hidden under both GEMMs ----
    int pos[16];
    unsigned int hv[16];
#pragma unroll
    for (int j = 0; j < 16; ++j) {
      int e = e0 + j;
      int src = ei[e];          // wave-uniform scalar load
      pos[j] = posOf[e];        // wave-uniform scalar load
      hv[j] = hb32[(size_t)src * 64 + lane];
    }

    // ---- A-fragments direct from global (row = e0+ln, 200B stride, 8B aligned) ----
    const float* ap = edge_attr + (size_t)(e0 + ln) * NUM_RBF;
    bf16x8 a0, a1;
    {
      const float2* p = (const float2*)(ap + grp * 8);
      float2 v0 = p[0], v1 = p[1], v2 = p[2], v3 = p[3];
      a0[0] = f2bf(v0.x); a0[1] = f2bf(v0.y); a0[2] = f2bf(v1.x); a0[3] = f2bf(v1.y);
      a0[4] = f2bf(v2.x); a0[5] = f2bf(v2.y); a0[6] = f2bf(v3.x); a0[7] = f2bf(v3.y);
    }
    a1 = (bf16x8){0, 0, 0, 0, 0, 0, 0, 0};
    if (grp < 2) {
      const float2* p = (const float2*)(ap + 32 + grp * 8);
      float2 v0 = p[0], v1 = p[1], v2 = p[2], v3 = p[3];
      a1[0] = f2bf(v0.x); a1[1] = f2bf(v0.y); a1[2] = f2bf(v1.x); a1[3] = f2bf(v1.y);
      a1[4] = f2bf(v2.x); a1[5] = f2bf(v2.y); a1[6] = f2bf(v3.x); a1[7] = f2bf(v3.y);
    } else if (grp == 2) {
      const float2* p = (const float2*)(ap + 48);
      float2 v0 = p[0];
      a1[0] = f2bf(v0.x); a1[1] = f2bf(v0.y);
    }

    // ---- GEMM1: T = tanh(A @ W1 + b1) -> own 16-row slab ----
#pragma unroll
    for (int ct = 0; ct < 8; ++ct) {
      f32x4 z = {0.f, 0.f, 0.f, 0.f};
      int c = ct * 16 + ln;
      bf16x8 b0 = *(const bf16x8*)&sW1t[c * 72 + grp * 8];
      bf16x8 b1 = *(const bf16x8*)&sW1t[c * 72 + 32 + grp * 8];
      z = mfma16(a0, b0, z);
      z = mfma16(a1, b1, z);
      float bias = sb1[c];
#pragma unroll
      for (int i = 0; i < 4; ++i) {
        int rl = wave * 16 + grp * 4 + i;
        sT[rl * 136 + c] = (unsigned short)f2bf(fast_tanh(z[i] + bias));
      }
    }
    WAVE_FENCE();  // T short-writes ordered before vector reads (same wave)

    // ---- GEMM2: Wf = (T @ W2 + b2) * C ----
    bf16x8 af[4];
#pragma unroll
    for (int ks = 0; ks < 4; ++ks)
      af[ks] = *(const bf16x8*)&sT[(wave * 16 + ln) * 136 + ks * 32 + grp * 8];
    WAVE_FENCE();  // af reads complete before slab overwritten below
    float Cv[4];
#pragma unroll
    for (int i = 0; i < 4; ++i)
      Cv[i] = 0.5f * (__cosf(edge_weight[e0 + grp * 4 + i] * 0.31415926535f) + 1.0f);
#pragma unroll
    for (int ct = 0; ct < 8; ++ct) {
      f32x4 z = {0.f, 0.f, 0.f, 0.f};
      int c = ct * 16 + ln;
#pragma unroll
      for (int ks = 0; ks < 4; ++ks) {
        bf16x8 b = *(const bf16x8*)&sW2t[c * 136 + ks * 32 + grp * 8];
        z = mfma16(af[ks], b, z);
      }
      float bias = sb2[c];
#pragma unroll
      for (int i = 0; i < 4; ++i) {
        int rl = wave * 16 + grp * 4 + i;
        sT[rl * 136 + c] = (unsigned short)f2bf((z[i] + bias) * Cv[i]);
      }
    }
    WAVE_FENCE();  // Wf short-writes ordered before uint writeout reads

    // ---- multiply with prefetched h rows, write msg at dst-sorted slot ----
#pragma unroll
    for (int j = 0; j < 16; ++j) {
      unsigned int w = *(const unsigned int*)&sT[(wave * 16 + j) * 136 + lane * 2];
      msg32[(size_t)pos[j] * 64 + lane] =
          pack2bf(bflo(w) * bflo(hv[j]), bfhi(w) * bfhi(hv[j]));
    }
    WAVE_FENCE();  // writeout reads done before next-iteration slab writes
  }
}

// ---------------- kernel 3: agg (f32, d_out rows) = segment-sum over CONTIGUOUS msg rows ----------------
__global__ __launch_bounds__(256) void segsum_kernel(
    const int* __restrict__ row_start,
    const unsigned int* __restrict__ msg32,
    float* __restrict__ aggf)   // = d_out, full f32 rows
{
  const int node = blockIdx.x * 4 + (threadIdx.x >> 6);
  const int lane = threadIdx.x & 63;
  const int eb = row_start[node], ee = row_start[node + 1];
  const int n = ee - eb;
  const unsigned int* p = msg32 + (size_t)eb * 64 + lane;
  float ax = 0.f, ay = 0.f, bx = 0.f, by = 0.f;
  int k = 0;
  for (; k + 1 < n; k += 2) {
    unsigned int u0 = p[(size_t)k * 64];
    unsigned int u1 = p[(size_t)(k + 1) * 64];
    ax += bflo(u0); ay += bfhi(u0);
    bx += bflo(u1); by += bfhi(u1);
  }
  if (k < n) {
    unsigned int u0 = p[(size_t)k * 64];
    ax += bflo(u0); ay += bfhi(u0);
  }
  ((float2*)aggf)[(size_t)node * 64 + lane] = make_float2(ax + bx, ay + by);
}

// ---------------- kernel 4 (R3-proven): out = tanh(agg@W_out+b_out) @ W_lin + b_lin ----------------
// agg and out may alias (both = d_out): no __restrict__, block-local rows only.
__global__ __launch_bounds__(256) void tail_kernel(
    const float* agg,
    const float* __restrict__ W_out, const float* __restrict__ b_out,
    const float* __restrict__ W_lin, const float* __restrict__ b_lin,
    float* out)
{
  __shared__ __align__(16) unsigned short sWo[128 * 136];
  __shared__ __align__(16) unsigned short sWl[128 * 136];
  __shared__ __align__(16) unsigned short sT[64 * 136];
  __shared__ float sbo[128], sbl[128];
  const int tid = threadIdx.x, wave = tid >> 6, lane = tid & 63;
  const int ln = lane & 15, grp = lane >> 4;
  const int r0 = blockIdx.x * 64;

  for (int idx = tid; idx < 128 * 128; idx += 256) {
    int k = idx >> 7, c = idx & 127;
    sWo[c * 136 + k] = f2bf(W_out[idx]);
    sWl[c * 136 + k] = f2bf(W_lin[idx]);
  }
  if (tid < 128) { sbo[tid] = b_out[tid]; sbl[tid] = b_lin[tid]; }
  __syncthreads();

  const size_t r = (size_t)r0 + wave * 16 + ln;
  f32x4 acc[8];
#pragma unroll
  for (int ct = 0; ct < 8; ++ct) acc[ct] = (f32x4){0.f, 0.f, 0.f, 0.f};
#pragma unroll
  for (int ks = 0; ks < 4; ++ks) {
    bf16x8 a = load8_f32_bf16(&agg[r * 128 + ks * 32 + grp * 8]);
#pragma unroll
    for (int ct = 0; ct < 8; ++ct) {
      bf16x8 b = *(const bf16x8*)&sWo[(ct * 16 + ln) * 136 + ks * 32 + grp * 8];
      acc[ct] = mfma16(a, b, acc[ct]);
    }
  }
#pragma unroll
  for (int ct = 0; ct < 8; ++ct) {
    int c = ct * 16 + ln;
    float bias = sbo[c];
#pragma unroll
    for (int i = 0; i < 4; ++i) {
      int rl = wave * 16 + grp * 4 + i;
      sT[rl * 136 + c] = f2bf(fast_tanh(acc[ct][i] + bias));
    }
  }
  __syncthreads();

  bf16x8 af[4];
#pragma unroll
  for (int ks = 0; ks < 4; ++ks)
    af[ks] = *(const bf16x8*)&sT[(wave * 16 + ln) * 136 + ks * 32 + grp * 8];
  f32x4 acc2[8];
#pragma unroll
  for (int ct = 0; ct < 8; ++ct) {
    f32x4 z = {0.f, 0.f, 0.f, 0.f};
    int c = ct * 16 + ln;
#pragma unroll
    for (int ks = 0; ks < 4; ++ks) {
      bf16x8 b = *(const bf16x8*)&sWl[c * 136 + ks * 32 + grp * 8];
      z = mfma16(af[ks], b, z);
    }
    acc2[ct] = z;
  }
  __syncthreads();  // all agg reads done before overwriting rows
#pragma unroll
  for (int ct = 0; ct < 8; ++ct) {
    int c = ct * 16 + ln;
    float bias = sbl[c];
#pragma unroll
    for (int i = 0; i < 4; ++i) {
      out[(size_t)(r0 + wave * 16 + grp * 4 + i) * 128 + c] = acc2[ct][i] + bias;
    }
  }
}

// ================= fallback path (atomic, bf16 h) =================
__global__ __launch_bounds__(256, 2) void edge_kernel(
    const float* __restrict__ edge_attr,
    const int*   __restrict__ edge_index,
    const float* __restrict__ edge_weight,
    const float* __restrict__ W_f1, const float* __restrict__ b_f1,
    const float* __restrict__ W_f2, const float* __restrict__ b_f2,
    const unsigned short* __restrict__ hb, float* __restrict__ agg)
{
  __shared__ __align__(16) unsigned short sW1t[128 * 72];
  __shared__ __align__(16) unsigned short sW2t[128 * 136];
  __shared__ __align__(16) unsigned short sT[64 * 136];
  __shared__ float sb1[128], sb2[128], sC[64];
  __shared__ int sSrc[64], sDst[64];

  const int tid = threadIdx.x, wave = tid >> 6, lane = tid & 63;
  const int ln = lane & 15, grp = lane >> 4;

  for (int idx = tid; idx < 128 * 64; idx += 256) {
    int k = idx >> 7, c = idx & 127;
    sW1t[c * 72 + k] = (k < NUM_RBF) ? f2bf(W_f1[k * 128 + c]) : (short)0;
  }
  for (int idx = tid; idx < 128 * 128; idx += 256) {
    int k = idx >> 7, c = idx & 127;
    sW2t[c * 136 + k] = f2bf(W_f2[idx]);
  }
  if (tid < 128) { sb1[tid] = b_f1[tid]; sb2[tid] = b_f2[tid]; }

  const int nTiles = N_EDGES / 64;
  for (int tile = blockIdx.x; tile < nTiles; tile += gridDim.x) {
    const int e0 = tile * 64;
    for (int idx = tid; idx < 64 * NUM_RBF; idx += 256) {
      int e = idx / NUM_RBF, k = idx - e * NUM_RBF;
      sT[e * 136 + k] = f2bf(edge_attr[(size_t)e0 * NUM_RBF + idx]);
    }
    for (int idx = tid; idx < 64 * 14; idx += 256) {
      int e = idx / 14, k = NUM_RBF + (idx - (idx / 14) * 14);
      sT[e * 136 + k] = 0;
    }
    if (tid < 64) {
      int e = e0 + tid;
      sC[tid] = 0.5f * (__cosf(edge_weight[e] * 0.31415926535f) + 1.0f);
      sSrc[tid] = edge_index[e];
      sDst[tid] = edge_index[N_EDGES + e];
    }
    __syncthreads();

    const int erow = wave * 16 + ln;
    bf16x8 a0 = *(const bf16x8*)&sT[erow * 136 + grp * 8];
    bf16x8 a1 = *(const bf16x8*)&sT[erow * 136 + 32 + grp * 8];
    __syncthreads();

    f32x4 acc[8];
#pragma unroll
    for (int ct = 0; ct < 8; ++ct) {
      f32x4 z = {0.f, 0.f, 0.f, 0.f};
      int c = ct * 16 + ln;
      bf16x8 b0 = *(const bf16x8*)&sW1t[c * 72 + grp * 8];
      bf16x8 b1 = *(const bf16x8*)&sW1t[c * 72 + 32 + grp * 8];
      z = mfma16(a0, b0, z);
      z = mfma16(a1, b1, z);
      acc[ct] = z;
    }
#pragma unroll
    for (int ct = 0; ct < 8; ++ct) {
      int c = ct * 16 + ln;
      float bias = sb1[c];
#pragma unroll
      for (int i = 0; i < 4; ++i) {
        int el = wave * 16 + grp * 4 + i;
        sT[el * 136 + c] = f2bf(fast_tanh(acc[ct][i] + bias));
      }
    }
    __syncthreads();

    bf16x8 af[4];
#pragma unroll
    for (int ks = 0; ks < 4; ++ks)
      af[ks] = *(const bf16x8*)&sT[erow * 136 + ks * 32 + grp * 8];
    f32x4 acc2[8];
#pragma unroll
    for (int ct = 0; ct < 8; ++ct) {
      f32x4 z = {0.f, 0.f, 0.f, 0.f};
      int c = ct * 16 + ln;
#pragma unroll
      for (int ks = 0; ks < 4; ++ks) {
        bf16x8 b = *(const bf16x8*)&sW2t[c * 136 + ks * 32 + grp * 8];
        z = mfma16(af[ks], b, z);
      }
      acc2[ct] = z;
    }
#pragma unroll
    for (int ct = 0; ct < 8; ++ct) {
      int c = ct * 16 + ln;
      float bias = sb2[c];
#pragma unroll
      for (int i = 0; i < 4; ++i) {
        int el = wave * 16 + grp * 4 + i;
        float wf = (acc2[ct][i] + bias) * sC[el];
        float m = bf2f(hb[(size_t)sSrc[el] * 128 + c]) * wf;
        atomicAdd(&agg[(size_t)sDst[el] * 128 + c], m);
      }
    }
    __syncthreads();
  }
}

extern "C" void kernel_launch(void* const* d_in, const int* in_sizes, int n_in,
                              void* d_out, int out_size, void* d_ws, size_t ws_size,
                              hipStream_t stream) {
  const float* x     = (const float*)d_in[0];
  const int*   ei    = (const int*)d_in[1];
  const float* ew    = (const float*)d_in[2];
  const float* ea    = (const float*)d_in[3];
  const float* W_f1  = (const float*)d_in[4];
  const float* b_f1  = (const float*)d_in[5];
  const float* W_f2  = (const float*)d_in[6];
  const float* b_f2  = (const float*)d_in[7];
  const float* W_in  = (const float*)d_in[8];
  const float* W_out = (const float*)d_in[9];
  const float* b_out = (const float*)d_in[10];
  const float* W_lin = (const float*)d_in[11];
  const float* b_lin = (const float*)d_in[12];

  const size_t HB_B  = (size_t)N_NODES * HIDDEN * 2;    // 10.24 MB  bf16 h
  const size_t MSG_B = (size_t)N_EDGES * HIDDEN * 2;    // 163.84 MB bf16 msg
  const size_t I_B   = (size_t)N_NODES * 4;             // 160 KB
  const size_t RS_B  = ((size_t)(N_NODES + 1) * 4 + 15) & ~(size_t)15;
  const size_t SB_B  = 1024;
  const size_t POS_B = (size_t)N_EDGES * 4;             // 2.56 MB
  const size_t NEED = HB_B + MSG_B + I_B + RS_B + I_B + I_B + SB_B + SB_B + POS_B;

  char* ws = (char*)d_ws;
  unsigned short* hb = (unsigned short*)ws;

  if (ws_size >= NEED) {
    char* q = ws + HB_B;
    unsigned short* msg = (unsigned short*)q;  q += MSG_B;
    int* hist      = (int*)q;                  q += I_B;
    int* row_start = (int*)q;                  q += RS_B;
    int* cursor    = (int*)q;                  q += I_B;
    int* tmp       = (int*)q;                  q += I_B;
    int* bsum      = (int*)q;                  q += SB_B;
    int* bpfx      = (int*)q;                  q += SB_B;
    int* posOf     = (int*)q;

    hipMemsetAsync(hist, 0, I_B, stream);
    hist_kernel<<<(N_EDGES + 255) / 256, 256, 0, stream>>>(ei, hist);
    scan1_kernel<<<NBLK_SCAN, 256, 0, stream>>>(hist, tmp, bsum);
    scan2_kernel<<<1, 256, 0, stream>>>(bsum, bpfx, row_start);
    scan3_kernel<<<NBLK_SCAN, 256, 0, stream>>>(hist, tmp, bpfx, row_start, cursor);
    perm_kernel<<<(N_EDGES + 255) / 256, 256, 0, stream>>>(ei, cursor, posOf);
    hproj_kernel<<<N_NODES / 64, 256, 0, stream>>>(x, W_in, hb);
    filt_kernel<<<256, 1024, 0, stream>>>(ea, ew, ei, posOf,
                                          (const unsigned int*)hb,
                                          W_f1, b_f1, W_f2, b_f2,
                                          (unsigned int*)msg);
    segsum_kernel<<<N_NODES / 4, 256, 0, stream>>>(row_start,
                                                   (const unsigned int*)msg,
                                                   (float*)d_out);
    tail_kernel<<<N_NODES / 64, 256, 0, stream>>>((const float*)d_out,
                                                  W_out, b_out, W_lin, b_lin,
                                                  (float*)d_out);
  } else {
    float* agg = (float*)(ws + HB_B);
    hipMemsetAsync(agg, 0, (size_t)N_NODES * HIDDEN * 4, stream);
    hproj_kernel<<<N_NODES / 64, 256, 0, stream>>>(x, W_in, hb);
    edge_kernel<<<512, 256, 0, stream>>>(ea, ei, ew, W_f1, b_f1, W_f2, b_f2, hb, agg);
    tail_kernel<<<N_NODES / 64, 256, 0, stream>>>(agg, W_out, b_out, W_lin, b_lin,
                                                  (float*)d_out);
  }
}

// Round 12
// 226.153 us; speedup vs baseline: 1.6717x; 1.0577x over previous
//
#include <hip/hip_runtime.h>
#include <hip/hip_bf16.h>

#define N_NODES 40000
#define N_EDGES 640000
#define HIDDEN  128
#define NUM_RBF 50
#define NBLK_SCAN 157  // ceil(40000/256)

typedef __attribute__((ext_vector_type(8))) short bf16x8;
typedef __attribute__((ext_vector_type(4))) float f32x4;

// zero-runtime compiler fence: orders LDS short-writes before differently-typed
// reads within a wave (TBAA otherwise allows reordering — the R4-R6 bug)
#define WAVE_FENCE() do { asm volatile("" ::: "memory"); \
                          __builtin_amdgcn_sched_barrier(0); } while (0)

__device__ __forceinline__ short f2bf(float f) {
  __hip_bfloat16 h = __float2bfloat16(f);
  return (short)__builtin_bit_cast(unsigned short, h);
}
__device__ __forceinline__ float bf2f(unsigned short u) {
  unsigned int v = ((unsigned int)u) << 16;
  return __builtin_bit_cast(float, v);
}
__device__ __forceinline__ float bflo(unsigned int u) {
  return __builtin_bit_cast(float, u << 16);
}
__device__ __forceinline__ float bfhi(unsigned int u) {
  return __builtin_bit_cast(float, u & 0xffff0000u);
}
__device__ __forceinline__ unsigned int pack2bf(float a, float b) {
  return (unsigned int)(unsigned short)f2bf(a) |
         ((unsigned int)(unsigned short)f2bf(b) << 16);
}

__device__ __forceinline__ float fast_tanh(float x) {
  float e = __expf(2.0f * x);
  return 1.0f - 2.0f * __builtin_amdgcn_rcpf(e + 1.0f);
}

__device__ __forceinline__ f32x4 mfma16(bf16x8 a, bf16x8 b, f32x4 c) {
  return __builtin_amdgcn_mfma_f32_16x16x32_bf16(a, b, c, 0, 0, 0);
}

__device__ __forceinline__ bf16x8 load8_f32_bf16(const float* p) {
  const float4 v0 = ((const float4*)p)[0];
  const float4 v1 = ((const float4*)p)[1];
  bf16x8 r;
  r[0] = f2bf(v0.x); r[1] = f2bf(v0.y); r[2] = f2bf(v0.z); r[3] = f2bf(v0.w);
  r[4] = f2bf(v1.x); r[5] = f2bf(v1.y); r[6] = f2bf(v1.z); r[7] = f2bf(v1.w);
  return r;
}

// ---------------- CSR build ----------------
__global__ __launch_bounds__(256) void hist_kernel(const int* __restrict__ ei,
                                                   int* __restrict__ hist) {
  int e = blockIdx.x * 256 + threadIdx.x;
  if (e < N_EDGES) atomicAdd(&hist[ei[N_EDGES + e]], 1);
}

__global__ __launch_bounds__(256) void scan1_kernel(const int* __restrict__ hist,
                                                    int* __restrict__ tmp,
                                                    int* __restrict__ bsum) {
  __shared__ int ls[256];
  const int t = threadIdx.x;
  const int i = blockIdx.x * 256 + t;
  int v = (i < N_NODES) ? hist[i] : 0;
  ls[t] = v;
  __syncthreads();
  for (int off = 1; off < 256; off <<= 1) {
    int u = (t >= off) ? ls[t - off] : 0;
    __syncthreads();
    ls[t] += u;
    __syncthreads();
  }
  if (i < N_NODES) tmp[i] = ls[t];
  if (t == 255) bsum[blockIdx.x] = ls[255];
}

__global__ __launch_bounds__(256) void scan2_kernel(const int* __restrict__ bsum,
                                                    int* __restrict__ bpfx,
                                                    int* __restrict__ row_start) {
  __shared__ int ls[256];
  const int t = threadIdx.x;
  int v = (t < NBLK_SCAN) ? bsum[t] : 0;
  ls[t] = v;
  __syncthreads();
  for (int off = 1; off < 256; off <<= 1) {
    int u = (t >= off) ? ls[t - off] : 0;
    __syncthreads();
    ls[t] += u;
    __syncthreads();
  }
  if (t < NBLK_SCAN) bpfx[t] = ls[t] - v;
  if (t == 255) row_start[N_NODES] = ls[255];
}

__global__ __launch_bounds__(256) void scan3_kernel(const int* __restrict__ hist,
                                                    const int* __restrict__ tmp,
                                                    const int* __restrict__ bpfx,
                                                    int* __restrict__ row_start,
                                                    int* __restrict__ cursor) {
  const int i = blockIdx.x * 256 + threadIdx.x;
  if (i < N_NODES) {
    int rs = tmp[i] - hist[i] + bpfx[blockIdx.x];
    row_start[i] = rs;
    cursor[i] = rs;
  }
}

// dst-sorted (edge, src) pairs
__global__ __launch_bounds__(256) void perm_kernel(const int* __restrict__ ei,
                                                   int* __restrict__ cursor,
                                                   int2* __restrict__ epk) {
  int e = blockIdx.x * 256 + threadIdx.x;
  if (e < N_EDGES) {
    int dst = ei[N_EDGES + e];
    int pos = atomicAdd(&cursor[dst], 1);
    epk[pos] = make_int2(e, ei[e]);
  }
}

// ---------------- kernel 1: hb = bf16(x @ W_in), direct stores (R3-proven mapping) ----------------
__global__ __launch_bounds__(256) void hproj_kernel(
    const float* __restrict__ x, const float* __restrict__ W_in,
    unsigned short* __restrict__ hb)
{
  __shared__ __align__(16) unsigned short sWt[128 * 136];
  const int tid = threadIdx.x, wave = tid >> 6, lane = tid & 63;
  const int ln = lane & 15, grp = lane >> 4;
  const int r0 = blockIdx.x * 64;

  for (int idx = tid; idx < 128 * 128; idx += 256) {
    int k = idx >> 7, c = idx & 127;
    sWt[c * 136 + k] = f2bf(W_in[idx]);
  }
  __syncthreads();

  const size_t r = (size_t)r0 + wave * 16 + ln;
  f32x4 acc[8];
#pragma unroll
  for (int ct = 0; ct < 8; ++ct) acc[ct] = (f32x4){0.f, 0.f, 0.f, 0.f};
#pragma unroll
  for (int ks = 0; ks < 4; ++ks) {
    bf16x8 a = load8_f32_bf16(&x[r * 128 + ks * 32 + grp * 8]);
#pragma unroll
    for (int ct = 0; ct < 8; ++ct) {
      bf16x8 b = *(const bf16x8*)&sWt[(ct * 16 + ln) * 136 + ks * 32 + grp * 8];
      acc[ct] = mfma16(a, b, acc[ct]);
    }
  }
#pragma unroll
  for (int ct = 0; ct < 8; ++ct) {
#pragma unroll
    for (int i = 0; i < 4; ++i) {
      hb[(size_t)(r0 + wave * 16 + grp * 4 + i) * 128 + ct * 16 + ln] =
          (unsigned short)f2bf(acc[ct][i]);
    }
  }
}

// ---------------- kernel 2: FUSED edge filter + h-multiply + segment-sum ----------------
// 1024 threads / 16 waves / 1 block per CU. Wave owns 4 consecutive nodes and
// their dst-sorted edge range; accumulates msg rows in registers; writes f32
// agg rows directly to d_out. No msg buffer, no atomics, barrier-free main loop.
__global__ __launch_bounds__(1024) void edgeagg_kernel(
    const float* __restrict__ edge_attr,
    const float* __restrict__ edge_weight,
    const int*  __restrict__ row_start,
    const int2* __restrict__ epk,
    const unsigned int* __restrict__ hb32,
    const float* __restrict__ W_f1, const float* __restrict__ b_f1,
    const float* __restrict__ W_f2, const float* __restrict__ b_f2,
    float* __restrict__ aggf)   // = d_out, full f32 rows
{
  __shared__ __align__(16) unsigned short sW1t[128 * 72];    // 18.4 KB
  __shared__ __align__(16) unsigned short sW2t[128 * 136];   // 34.8 KB
  __shared__ __align__(16) unsigned short sT[256 * 136];     // 69.6 KB: 16 wave-slabs
  __shared__ float sb1[128], sb2[128];

  const int tid = threadIdx.x, wave = tid >> 6, lane = tid & 63;
  const int ln = lane & 15, grp = lane >> 4;

  for (int idx = tid; idx < 128 * 64; idx += 1024) {
    int k = idx >> 7, c = idx & 127;
    sW1t[c * 72 + k] = (k < NUM_RBF) ? f2bf(W_f1[k * 128 + c]) : (short)0;
  }
  for (int idx = tid; idx < 128 * 128; idx += 1024) {
    int k = idx >> 7, c = idx & 127;
    sW2t[c * 136 + k] = f2bf(W_f2[idx]);
  }
  if (tid < 128) { sb1[tid] = b_f1[tid]; sb2[tid] = b_f2[tid]; }
  __syncthreads();  // the only barrier in the kernel

  const int gw = blockIdx.x * 16 + wave;    // global wave id
  const int nw = gridDim.x * 16;
  const int nGroups = N_NODES / 4;          // 10000 node-groups of 4

  for (int ng = gw; ng < nGroups; ng += nw) {
    const int n0 = ng * 4;
    const int rs0 = row_start[n0],     rs1 = row_start[n0 + 1];
    const int rs2 = row_start[n0 + 2], rs3 = row_start[n0 + 3];
    const int rs4 = row_start[n0 + 4];

    float ax = 0.f, ay = 0.f;
    int cur = 0;
    int nb = rs1;  // next flush boundary (select-chain, no dynamic array idx)

    for (int gb = rs0; gb < rs4; gb += 16) {
      const int lim = (rs4 - gb < 16) ? (rs4 - gb) : 16;

      // ---- prefetch h rows (uniform epk loads, per-lane column gather) ----
      unsigned int hv[16];
#pragma unroll
      for (int j = 0; j < 16; ++j) {
        int s = gb + j; if (s >= rs4) s = rs4 - 1;
        int src = epk[s].y;               // wave-uniform
        hv[j] = hb32[(size_t)src * 64 + lane];
      }

      // ---- per-lane edge id for A-row + cutoff ----
      int sl = gb + ln; if (sl >= rs4) sl = rs4 - 1;
      const int eA = epk[sl].x;           // per-lane (lanes mod 16 pattern)
      const float Cw =
          0.5f * (__cosf(edge_weight[eA] * 0.31415926535f) + 1.0f);

      // ---- A-fragments from gathered edge_attr rows (200B row, 8B aligned) ----
      const float* ap = edge_attr + (size_t)eA * NUM_RBF;
      bf16x8 a0, a1;
      {
        const float2* p = (const float2*)(ap + grp * 8);
        float2 v0 = p[0], v1 = p[1], v2 = p[2], v3 = p[3];
        a0[0] = f2bf(v0.x); a0[1] = f2bf(v0.y); a0[2] = f2bf(v1.x); a0[3] = f2bf(v1.y);
        a0[4] = f2bf(v2.x); a0[5] = f2bf(v2.y); a0[6] = f2bf(v3.x); a0[7] = f2bf(v3.y);
      }
      a1 = (bf16x8){0, 0, 0, 0, 0, 0, 0, 0};
      if (grp < 2) {
        const float2* p = (const float2*)(ap + 32 + grp * 8);
        float2 v0 = p[0], v1 = p[1], v2 = p[2], v3 = p[3];
        a1[0] = f2bf(v0.x); a1[1] = f2bf(v0.y); a1[2] = f2bf(v1.x); a1[3] = f2bf(v1.y);
        a1[4] = f2bf(v2.x); a1[5] = f2bf(v2.y); a1[6] = f2bf(v3.x); a1[7] = f2bf(v3.y);
      } else if (grp == 2) {
        const float2* p = (const float2*)(ap + 48);
        float2 v0 = p[0];
        a1[0] = f2bf(v0.x); a1[1] = f2bf(v0.y);
      }

      // ---- GEMM1: T = tanh(A @ W1 + b1) -> own 16-row slab ----
#pragma unroll
      for (int ct = 0; ct < 8; ++ct) {
        f32x4 z = {0.f, 0.f, 0.f, 0.f};
        int c = ct * 16 + ln;
        bf16x8 b0 = *(const bf16x8*)&sW1t[c * 72 + grp * 8];
        bf16x8 b1 = *(const bf16x8*)&sW1t[c * 72 + 32 + grp * 8];
        z = mfma16(a0, b0, z);
        z = mfma16(a1, b1, z);
        float bias = sb1[c];
#pragma unroll
        for (int i = 0; i < 4; ++i) {
          int rl = wave * 16 + grp * 4 + i;
          sT[rl * 136 + c] = (unsigned short)f2bf(fast_tanh(z[i] + bias));
        }
      }
      WAVE_FENCE();  // T short-writes ordered before vector reads (same wave)

      // ---- GEMM2: Wf = T @ W2 + b2 (C applied in the walk) ----
      bf16x8 af[4];
#pragma unroll
      for (int ks = 0; ks < 4; ++ks)
        af[ks] = *(const bf16x8*)&sT[(wave * 16 + ln) * 136 + ks * 32 + grp * 8];
      WAVE_FENCE();  // af reads complete before slab overwritten below
#pragma unroll
      for (int ct = 0; ct < 8; ++ct) {
        f32x4 z = {0.f, 0.f, 0.f, 0.f};
        int c = ct * 16 + ln;
#pragma unroll
        for (int ks = 0; ks < 4; ++ks) {
          bf16x8 b = *(const bf16x8*)&sW2t[c * 136 + ks * 32 + grp * 8];
          z = mfma16(af[ks], b, z);
        }
        float bias = sb2[c];
#pragma unroll
        for (int i = 0; i < 4; ++i) {
          int rl = wave * 16 + grp * 4 + i;
          sT[rl * 136 + c] = (unsigned short)f2bf(z[i] + bias);
        }
      }
      WAVE_FENCE();  // Wf short-writes ordered before uint walk reads

      // ---- walk: acc += C * Wf_row * h_row ; flush at node boundaries ----
#pragma unroll
      for (int j = 0; j < 16; ++j) {
        if (j < lim) {
          while (cur < 4 && gb + j == nb) {   // wave-uniform flush
            ((float2*)aggf)[(size_t)(n0 + cur) * 64 + lane] =
                make_float2(ax, ay);
            ax = 0.f; ay = 0.f;
            ++cur;
            nb = (cur == 1) ? rs2 : (cur == 2) ? rs3 : rs4;
          }
          unsigned int w = *(const unsigned int*)&sT[(wave * 16 + j) * 136 + lane * 2];
          float C = __shfl(Cw, j, 64);        // lane j holds C for row j
          ax = fmaf(C * bflo(w), bflo(hv[j]), ax);
          ay = fmaf(C * bfhi(w), bfhi(hv[j]), ay);
        }
      }
      WAVE_FENCE();  // walk reads done before next-group slab writes
    }

    // drain: current node, then zero rows for any trailing empty nodes
    while (cur < 4) {
      ((float2*)aggf)[(size_t)(n0 + cur) * 64 + lane] = make_float2(ax, ay);
      ax = 0.f; ay = 0.f;
      ++cur;
    }
  }
}

// ---------------- kernel 3 (R3-proven): out = tanh(agg@W_out+b_out) @ W_lin + b_lin ----------------
// agg and out may alias (both = d_out): no __restrict__, block-local rows only.
__global__ __launch_bounds__(256) void tail_kernel(
    const float* agg,
    const float* __restrict__ W_out, const float* __restrict__ b_out,
    const float* __restrict__ W_lin, const float* __restrict__ b_lin,
    float* out)
{
  __shared__ __align__(16) unsigned short sWo[128 * 136];
  __shared__ __align__(16) unsigned short sWl[128 * 136];
  __shared__ __align__(16) unsigned short sT[64 * 136];
  __shared__ float sbo[128], sbl[128];
  const int tid = threadIdx.x, wave = tid >> 6, lane = tid & 63;
  const int ln = lane & 15, grp = lane >> 4;
  const int r0 = blockIdx.x * 64;

  for (int idx = tid; idx < 128 * 128; idx += 256) {
    int k = idx >> 7, c = idx & 127;
    sWo[c * 136 + k] = f2bf(W_out[idx]);
    sWl[c * 136 + k] = f2bf(W_lin[idx]);
  }
  if (tid < 128) { sbo[tid] = b_out[tid]; sbl[tid] = b_lin[tid]; }
  __syncthreads();

  const size_t r = (size_t)r0 + wave * 16 + ln;
  f32x4 acc[8];
#pragma unroll
  for (int ct = 0; ct < 8; ++ct) acc[ct] = (f32x4){0.f, 0.f, 0.f, 0.f};
#pragma unroll
  for (int ks = 0; ks < 4; ++ks) {
    bf16x8 a = load8_f32_bf16(&agg[r * 128 + ks * 32 + grp * 8]);
#pragma unroll
    for (int ct = 0; ct < 8; ++ct) {
      bf16x8 b = *(const bf16x8*)&sWo[(ct * 16 + ln) * 136 + ks * 32 + grp * 8];
      acc[ct] = mfma16(a, b, acc[ct]);
    }
  }
#pragma unroll
  for (int ct = 0; ct < 8; ++ct) {
    int c = ct * 16 + ln;
    float bias = sbo[c];
#pragma unroll
    for (int i = 0; i < 4; ++i) {
      int rl = wave * 16 + grp * 4 + i;
      sT[rl * 136 + c] = f2bf(fast_tanh(acc[ct][i] + bias));
    }
  }
  __syncthreads();

  bf16x8 af[4];
#pragma unroll
  for (int ks = 0; ks < 4; ++ks)
    af[ks] = *(const bf16x8*)&sT[(wave * 16 + ln) * 136 + ks * 32 + grp * 8];
  f32x4 acc2[8];
#pragma unroll
  for (int ct = 0; ct < 8; ++ct) {
    f32x4 z = {0.f, 0.f, 0.f, 0.f};
    int c = ct * 16 + ln;
#pragma unroll
    for (int ks = 0; ks < 4; ++ks) {
      bf16x8 b = *(const bf16x8*)&sWl[c * 136 + ks * 32 + grp * 8];
      z = mfma16(af[ks], b, z);
    }
    acc2[ct] = z;
  }
  __syncthreads();  // all agg reads done before overwriting rows
#pragma unroll
  for (int ct = 0; ct < 8; ++ct) {
    int c = ct * 16 + ln;
    float bias = sbl[c];
#pragma unroll
    for (int i = 0; i < 4; ++i) {
      out[(size_t)(r0 + wave * 16 + grp * 4 + i) * 128 + c] = acc2[ct][i] + bias;
    }
  }
}

// ================= fallback path (atomic, bf16 h) =================
__global__ __launch_bounds__(256, 2) void edge_kernel(
    const float* __restrict__ edge_attr,
    const int*   __restrict__ edge_index,
    const float* __restrict__ edge_weight,
    const float* __restrict__ W_f1, const float* __restrict__ b_f1,
    const float* __restrict__ W_f2, const float* __restrict__ b_f2,
    const unsigned short* __restrict__ hb, float* __restrict__ agg)
{
  __shared__ __align__(16) unsigned short sW1t[128 * 72];
  __shared__ __align__(16) unsigned short sW2t[128 * 136];
  __shared__ __align__(16) unsigned short sT[64 * 136];
  __shared__ float sb1[128], sb2[128], sC[64];
  __shared__ int sSrc[64], sDst[64];

  const int tid = threadIdx.x, wave = tid >> 6, lane = tid & 63;
  const int ln = lane & 15, grp = lane >> 4;

  for (int idx = tid; idx < 128 * 64; idx += 256) {
    int k = idx >> 7, c = idx & 127;
    sW1t[c * 72 + k] = (k < NUM_RBF) ? f2bf(W_f1[k * 128 + c]) : (short)0;
  }
  for (int idx = tid; idx < 128 * 128; idx += 256) {
    int k = idx >> 7, c = idx & 127;
    sW2t[c * 136 + k] = f2bf(W_f2[idx]);
  }
  if (tid < 128) { sb1[tid] = b_f1[tid]; sb2[tid] = b_f2[tid]; }

  const int nTiles = N_EDGES / 64;
  for (int tile = blockIdx.x; tile < nTiles; tile += gridDim.x) {
    const int e0 = tile * 64;
    for (int idx = tid; idx < 64 * NUM_RBF; idx += 256) {
      int e = idx / NUM_RBF, k = idx - e * NUM_RBF;
      sT[e * 136 + k] = f2bf(edge_attr[(size_t)e0 * NUM_RBF + idx]);
    }
    for (int idx = tid; idx < 64 * 14; idx += 256) {
      int e = idx / 14, k = NUM_RBF + (idx - (idx / 14) * 14);
      sT[e * 136 + k] = 0;
    }
    if (tid < 64) {
      int e = e0 + tid;
      sC[tid] = 0.5f * (__cosf(edge_weight[e] * 0.31415926535f) + 1.0f);
      sSrc[tid] = edge_index[e];
      sDst[tid] = edge_index[N_EDGES + e];
    }
    __syncthreads();

    const int erow = wave * 16 + ln;
    bf16x8 a0 = *(const bf16x8*)&sT[erow * 136 + grp * 8];
    bf16x8 a1 = *(const bf16x8*)&sT[erow * 136 + 32 + grp * 8];
    __syncthreads();

    f32x4 acc[8];
#pragma unroll
    for (int ct = 0; ct < 8; ++ct) {
      f32x4 z = {0.f, 0.f, 0.f, 0.f};
      int c = ct * 16 + ln;
      bf16x8 b0 = *(const bf16x8*)&sW1t[c * 72 + grp * 8];
      bf16x8 b1 = *(const bf16x8*)&sW1t[c * 72 + 32 + grp * 8];
      z = mfma16(a0, b0, z);
      z = mfma16(a1, b1, z);
      acc[ct] = z;
    }
#pragma unroll
    for (int ct = 0; ct < 8; ++ct) {
      int c = ct * 16 + ln;
      float bias = sb1[c];
#pragma unroll
      for (int i = 0; i < 4; ++i) {
        int el = wave * 16 + grp * 4 + i;
        sT[el * 136 + c] = f2bf(fast_tanh(acc[ct][i] + bias));
      }
    }
    __syncthreads();

    bf16x8 af[4];
#pragma unroll
    for (int ks = 0; ks < 4; ++ks)
      af[ks] = *(const bf16x8*)&sT[erow * 136 + ks * 32 + grp * 8];
    f32x4 acc2[8];
#pragma unroll
    for (int ct = 0; ct < 8; ++ct) {
      f32x4 z = {0.f, 0.f, 0.f, 0.f};
      int c = ct * 16 + ln;
#pragma unroll
      for (int ks = 0; ks < 4; ++ks) {
        bf16x8 b = *(const bf16x8*)&sW2t[c * 136 + ks * 32 + grp * 8];
        z = mfma16(af[ks], b, z);
      }
      acc2[ct] = z;
    }
#pragma unroll
    for (int ct = 0; ct < 8; ++ct) {
      int c = ct * 16 + ln;
      float bias = sb2[c];
#pragma unroll
      for (int i = 0; i < 4; ++i) {
        int el = wave * 16 + grp * 4 + i;
        float wf = (acc2[ct][i] + bias) * sC[el];
        float m = bf2f(hb[(size_t)sSrc[el] * 128 + c]) * wf;
        atomicAdd(&agg[(size_t)sDst[el] * 128 + c], m);
      }
    }
    __syncthreads();
  }
}

extern "C" void kernel_launch(void* const* d_in, const int* in_sizes, int n_in,
                              void* d_out, int out_size, void* d_ws, size_t ws_size,
                              hipStream_t stream) {
  const float* x     = (const float*)d_in[0];
  const int*   ei    = (const int*)d_in[1];
  const float* ew    = (const float*)d_in[2];
  const float* ea    = (const float*)d_in[3];
  const float* W_f1  = (const float*)d_in[4];
  const float* b_f1  = (const float*)d_in[5];
  const float* W_f2  = (const float*)d_in[6];
  const float* b_f2  = (const float*)d_in[7];
  const float* W_in  = (const float*)d_in[8];
  const float* W_out = (const float*)d_in[9];
  const float* b_out = (const float*)d_in[10];
  const float* W_lin = (const float*)d_in[11];
  const float* b_lin = (const float*)d_in[12];

  const size_t HB_B  = (size_t)N_NODES * HIDDEN * 2;    // 10.24 MB  bf16 h
  const size_t I_B   = (size_t)N_NODES * 4;             // 160 KB
  const size_t RS_B  = ((size_t)(N_NODES + 1) * 4 + 15) & ~(size_t)15;
  const size_t SB_B  = 1024;
  const size_t EPK_B = (size_t)N_EDGES * 8;             // 5.12 MB
  const size_t NEED = HB_B + I_B + RS_B + I_B + I_B + SB_B + SB_B + EPK_B;

  char* ws = (char*)d_ws;
  unsigned short* hb = (unsigned short*)ws;

  if (ws_size >= NEED) {
    char* q = ws + HB_B;
    int* hist      = (int*)q;                  q += I_B;
    int* row_start = (int*)q;                  q += RS_B;
    int* cursor    = (int*)q;                  q += I_B;
    int* tmp       = (int*)q;                  q += I_B;
    int* bsum      = (int*)q;                  q += SB_B;
    int* bpfx      = (int*)q;                  q += SB_B;
    int2* epk      = (int2*)q;

    hipMemsetAsync(hist, 0, I_B, stream);
    hist_kernel<<<(N_EDGES + 255) / 256, 256, 0, stream>>>(ei, hist);
    scan1_kernel<<<NBLK_SCAN, 256, 0, stream>>>(hist, tmp, bsum);
    scan2_kernel<<<1, 256, 0, stream>>>(bsum, bpfx, row_start);
    scan3_kernel<<<NBLK_SCAN, 256, 0, stream>>>(hist, tmp, bpfx, row_start, cursor);
    perm_kernel<<<(N_EDGES + 255) / 256, 256, 0, stream>>>(ei, cursor, epk);
    hproj_kernel<<<N_NODES / 64, 256, 0, stream>>>(x, W_in, hb);
    edgeagg_kernel<<<256, 1024, 0, stream>>>(ea, ew, row_start, epk,
                                             (const unsigned int*)hb,
                                             W_f1, b_f1, W_f2, b_f2,
                                             (float*)d_out);
    tail_kernel<<<N_NODES / 64, 256, 0, stream>>>((const float*)d_out,
                                                  W_out, b_out, W_lin, b_lin,
                                                  (float*)d_out);
  } else {
    float* agg = (float*)(ws + HB_B);
    hipMemsetAsync(agg, 0, (size_t)N_NODES * HIDDEN * 4, stream);
    hproj_kernel<<<N_NODES / 64, 256, 0, stream>>>(x, W_in, hb);
    edge_kernel<<<512, 256, 0, stream>>>(ea, ei, ew, W_f1, b_f1, W_f2, b_f2, hb, agg);
    tail_kernel<<<N_NODES / 64, 256, 0, stream>>>(agg, W_out, b_out, W_lin, b_lin,
                                                  (float*)d_out);
  }
}